// Round 22
// baseline (204.317 us; speedup 1.0000x reference)
//
#include <hip/hip_runtime.h>
#include <hip/hip_bf16.h>

// BasketballGNN R22: aggV gather-ILP fix (issue 8 row-gathers before accumulating).
// R21 evidence: k_aggV 59us latency-bound (VALU 45%, occ 36%); inner `unroll 1` loop
// held ONE gather in flight per wave. Now all 8 batches issue up-front (vmcnt queue
// depth 8). Rest of the pipeline frozen from R21 (MFMA enc + upd verified).

__device__ inline float bflo(unsigned u){ return __uint_as_float(u << 16); }
__device__ inline float bfhi(unsigned u){ return __uint_as_float(u & 0xffff0000u); }
__device__ inline float gbf(const unsigned short* p){ return __uint_as_float(((unsigned)(*p)) << 16); }
__device__ inline unsigned short f2bu(float f){
  unsigned x = __float_as_uint(f);
  unsigned r = (x + 0x7fffu + ((x >> 16) & 1u)) >> 16;  // RNE
  return (unsigned short)r;
}

typedef __attribute__((ext_vector_type(8))) short short8v;
typedef __attribute__((ext_vector_type(4))) float float4v;

// detect edge-index width (int64 -> odd 32b words all zero). 1 = int32, 0 = int64.
__device__ inline int detect_i32(const int* ei, int nwords, int tid, int* sflag){
  if (tid == 0) *sflag = 0;
  __syncthreads();
  int acc = 0;
  for (int i = tid; i < nwords; i += 256)
    if (i & 1) acc |= ei[i];
  if (acc) atomicOr(sflag, 1);
  __syncthreads();
  return *sflag;
}

__device__ inline void load_rc32(const int* ei, int is32, int e, int E, int N, int& r, int& c){
  if (is32){ r = ei[e]; c = ei[(size_t)E + e]; }
  else     { r = ei[2*(size_t)e]; c = ei[2*((size_t)E + (size_t)e)]; }
  r = min(max(r, 0), N-1); c = min(max(c, 0), N-1);
}

// ------- k_encM: MFMA encoder + u,v (R21, unchanged) -------
template<int VPREC>
__global__ __launch_bounds__(256) void k_encM(
    const float* __restrict__ x,    // [N,6]
    const float* __restrict__ eW1, const float* __restrict__ eb1,
    const float* __restrict__ eW2, const float* __restrict__ eb2,
    const float* __restrict__ mW1,  // [128,64]
    unsigned short* __restrict__ hb,
    unsigned short* __restrict__ uh,
    float* __restrict__ vf, unsigned short* __restrict__ vh,
    int N)
{
  __shared__ unsigned short F_lds[64*40];
  __shared__ unsigned short W1T[64*40];
  __shared__ unsigned short W2T[64*72];
  __shared__ unsigned short loT[64*72];
  __shared__ unsigned short hiT[64*72];
  __shared__ unsigned short S_lds[4][16*72];
  __shared__ float b1s[64], b2s[64];

  int tid = threadIdx.x, lane = tid & 63, w = tid >> 6;
  int gbase = blockIdx.x * 64;

  for (int i = tid; i < 64*40; i += 256){
    int nl = i / 40, k = i % 40;
    int ng = gbase + nl;
    unsigned short val = 0;
    if (ng < N && k < 6) val = f2bu(x[(size_t)ng*6 + k]);
    F_lds[i] = val;
  }
  for (int i = tid; i < 64*40; i += 256){
    int j = i / 40, k = i % 40;
    W1T[i] = (k < 6) ? f2bu(eW1[k*64 + j]) : (unsigned short)0;
  }
  for (int i = tid; i < 64*64; i += 256){
    int k = i >> 6, c = i & 63;
    W2T[c*72 + k] = f2bu(eW2[i]);
    loT[c*72 + k] = f2bu(mW1[i]);
    hiT[c*72 + k] = f2bu(mW1[64*64 + i]);
  }
  if (tid < 64){ b1s[tid] = eb1[tid]; b2s[tid] = eb2[tid]; }
  __syncthreads();

  int r  = lane & 15;
  int kg = lane >> 4;
  int wb = w * 16;

  {
    short8v a = *reinterpret_cast<const short8v*>(&F_lds[(wb + r)*40 + kg*8]);
    float4v c0 = {0.f,0.f,0.f,0.f}, c1 = c0, c2 = c0, c3 = c0;
    short8v b0 = *reinterpret_cast<const short8v*>(&W1T[( 0 + r)*40 + kg*8]);
    short8v b1v= *reinterpret_cast<const short8v*>(&W1T[(16 + r)*40 + kg*8]);
    short8v b2v= *reinterpret_cast<const short8v*>(&W1T[(32 + r)*40 + kg*8]);
    short8v b3v= *reinterpret_cast<const short8v*>(&W1T[(48 + r)*40 + kg*8]);
    c0 = __builtin_amdgcn_mfma_f32_16x16x32_bf16(a, b0, c0, 0, 0, 0);
    c1 = __builtin_amdgcn_mfma_f32_16x16x32_bf16(a, b1v, c1, 0, 0, 0);
    c2 = __builtin_amdgcn_mfma_f32_16x16x32_bf16(a, b2v, c2, 0, 0, 0);
    c3 = __builtin_amdgcn_mfma_f32_16x16x32_bf16(a, b3v, c3, 0, 0, 0);
    float bb0 = b1s[ 0 + r], bb1 = b1s[16 + r], bb2 = b1s[32 + r], bb3 = b1s[48 + r];
    #pragma unroll
    for (int i = 0; i < 4; i++){
      int row = kg*4 + i;
      S_lds[w][row*72 +  0 + r] = f2bu(fmaxf(c0[i] + bb0, 0.f));
      S_lds[w][row*72 + 16 + r] = f2bu(fmaxf(c1[i] + bb1, 0.f));
      S_lds[w][row*72 + 32 + r] = f2bu(fmaxf(c2[i] + bb2, 0.f));
      S_lds[w][row*72 + 48 + r] = f2bu(fmaxf(c3[i] + bb3, 0.f));
    }
  }

  float hv[4][4];
  {
    float4v c0 = {0.f,0.f,0.f,0.f}, c1 = c0, c2 = c0, c3 = c0;
    #pragma unroll
    for (int kt = 0; kt < 2; kt++){
      short8v a2 = *reinterpret_cast<const short8v*>(&S_lds[w][r*72 + kt*32 + kg*8]);
      short8v d0 = *reinterpret_cast<const short8v*>(&W2T[( 0 + r)*72 + kt*32 + kg*8]);
      short8v d1 = *reinterpret_cast<const short8v*>(&W2T[(16 + r)*72 + kt*32 + kg*8]);
      short8v d2 = *reinterpret_cast<const short8v*>(&W2T[(32 + r)*72 + kt*32 + kg*8]);
      short8v d3 = *reinterpret_cast<const short8v*>(&W2T[(48 + r)*72 + kt*32 + kg*8]);
      c0 = __builtin_amdgcn_mfma_f32_16x16x32_bf16(a2, d0, c0, 0, 0, 0);
      c1 = __builtin_amdgcn_mfma_f32_16x16x32_bf16(a2, d1, c1, 0, 0, 0);
      c2 = __builtin_amdgcn_mfma_f32_16x16x32_bf16(a2, d2, c2, 0, 0, 0);
      c3 = __builtin_amdgcn_mfma_f32_16x16x32_bf16(a2, d3, c3, 0, 0, 0);
    }
    float bb0 = b2s[ 0 + r], bb1 = b2s[16 + r], bb2 = b2s[32 + r], bb3 = b2s[48 + r];
    #pragma unroll
    for (int i = 0; i < 4; i++){
      hv[0][i] = c0[i] + bb0; hv[1][i] = c1[i] + bb1;
      hv[2][i] = c2[i] + bb2; hv[3][i] = c3[i] + bb3;
    }
  }
  #pragma unroll
  for (int i = 0; i < 4; i++){
    int row = kg*4 + i;
    int ng = gbase + wb + row;
    unsigned short h0 = f2bu(hv[0][i]), h1 = f2bu(hv[1][i]);
    unsigned short h2 = f2bu(hv[2][i]), h3 = f2bu(hv[3][i]);
    if (ng < N){
      hb[(size_t)ng*64 +  0 + r] = h0;
      hb[(size_t)ng*64 + 16 + r] = h1;
      hb[(size_t)ng*64 + 32 + r] = h2;
      hb[(size_t)ng*64 + 48 + r] = h3;
    }
    S_lds[w][row*72 +  0 + r] = h0;
    S_lds[w][row*72 + 16 + r] = h1;
    S_lds[w][row*72 + 32 + r] = h2;
    S_lds[w][row*72 + 48 + r] = h3;
  }

  float4v u0 = {0.f,0.f,0.f,0.f}, u1 = u0, u2 = u0, u3 = u0;
  float4v v0 = u0, v1 = u0, v2 = u0, v3 = u0;
  #pragma unroll
  for (int kt = 0; kt < 2; kt++){
    short8v a3 = *reinterpret_cast<const short8v*>(&S_lds[w][r*72 + kt*32 + kg*8]);
    short8v l0 = *reinterpret_cast<const short8v*>(&loT[( 0 + r)*72 + kt*32 + kg*8]);
    short8v l1 = *reinterpret_cast<const short8v*>(&loT[(16 + r)*72 + kt*32 + kg*8]);
    short8v l2 = *reinterpret_cast<const short8v*>(&loT[(32 + r)*72 + kt*32 + kg*8]);
    short8v l3 = *reinterpret_cast<const short8v*>(&loT[(48 + r)*72 + kt*32 + kg*8]);
    short8v g0 = *reinterpret_cast<const short8v*>(&hiT[( 0 + r)*72 + kt*32 + kg*8]);
    short8v g1 = *reinterpret_cast<const short8v*>(&hiT[(16 + r)*72 + kt*32 + kg*8]);
    short8v g2 = *reinterpret_cast<const short8v*>(&hiT[(32 + r)*72 + kt*32 + kg*8]);
    short8v g3 = *reinterpret_cast<const short8v*>(&hiT[(48 + r)*72 + kt*32 + kg*8]);
    u0 = __builtin_amdgcn_mfma_f32_16x16x32_bf16(a3, l0, u0, 0, 0, 0);
    u1 = __builtin_amdgcn_mfma_f32_16x16x32_bf16(a3, l1, u1, 0, 0, 0);
    u2 = __builtin_amdgcn_mfma_f32_16x16x32_bf16(a3, l2, u2, 0, 0, 0);
    u3 = __builtin_amdgcn_mfma_f32_16x16x32_bf16(a3, l3, u3, 0, 0, 0);
    v0 = __builtin_amdgcn_mfma_f32_16x16x32_bf16(a3, g0, v0, 0, 0, 0);
    v1 = __builtin_amdgcn_mfma_f32_16x16x32_bf16(a3, g1, v1, 0, 0, 0);
    v2 = __builtin_amdgcn_mfma_f32_16x16x32_bf16(a3, g2, v2, 0, 0, 0);
    v3 = __builtin_amdgcn_mfma_f32_16x16x32_bf16(a3, g3, v3, 0, 0, 0);
  }
  #pragma unroll
  for (int i = 0; i < 4; i++){
    int ng = gbase + wb + kg*4 + i;
    if (ng < N){
      uh[(size_t)ng*64 +  0 + r] = f2bu(u0[i]);
      uh[(size_t)ng*64 + 16 + r] = f2bu(u1[i]);
      uh[(size_t)ng*64 + 32 + r] = f2bu(u2[i]);
      uh[(size_t)ng*64 + 48 + r] = f2bu(u3[i]);
      if (VPREC){
        vf[(size_t)ng*64 +  0 + r] = v0[i];
        vf[(size_t)ng*64 + 16 + r] = v1[i];
        vf[(size_t)ng*64 + 32 + r] = v2[i];
        vf[(size_t)ng*64 + 48 + r] = v3[i];
      } else {
        vh[(size_t)ng*64 +  0 + r] = f2bu(v0[i]);
        vh[(size_t)ng*64 + 16 + r] = f2bu(v1[i]);
        vh[(size_t)ng*64 + 32 + r] = f2bu(v2[i]);
        vh[(size_t)ng*64 + 48 + r] = f2bu(v3[i]);
      }
    }
  }
}

// ------- k_hist: coarse histogram (R14, unchanged) -------
__global__ __launch_bounds__(256) void k_hist(
    const int* __restrict__ ei,
    int* __restrict__ BH,
    int E, int N, int nb1, int nwords)
{
  __shared__ int hist[1024];
  __shared__ int sflag;
  int tid = threadIdx.x;
  for (int i = tid; i < nb1; i += 256) hist[i] = 0;
  int is32 = detect_i32(ei, nwords, tid, &sflag);
  int j = blockIdx.x;
  for (int e = j*256 + tid; e < E; e += 1024*256){
    int c = is32 ? ei[(size_t)E + e] : ei[2*((size_t)E + (size_t)e)];
    c = min(max(c, 0), N-1);
    atomicAdd(&hist[c >> 8], 1);
  }
  __syncthreads();
  int jm = ((j & 7) << 7) | (j >> 3);
  for (int i = tid; i < nb1; i += 256) BH[(size_t)i*1024 + jm] = hist[i];
}

// ---------------- scans ----------------
__global__ void k_scan1(const int* __restrict__ counts, int* __restrict__ offsets,
                        int* __restrict__ part, int M)
{
  __shared__ int tsum[256];
  int t = threadIdx.x;
  int base = blockIdx.x*2048 + t*8;
  int v[8]; int s = 0;
  #pragma unroll
  for (int i = 0; i < 8; i++){ int idx = base+i; v[i] = (idx < M) ? counts[idx] : 0; }
  #pragma unroll
  for (int i = 0; i < 8; i++){ int t0 = v[i]; v[i] = s; s += t0; }
  tsum[t] = s;
  __syncthreads();
  for (int d = 1; d < 256; d <<= 1){
    int y = (t >= d) ? tsum[t-d] : 0;
    __syncthreads();
    tsum[t] += y;
    __syncthreads();
  }
  int tpre = tsum[t] - s;
  #pragma unroll
  for (int i = 0; i < 8; i++){ int idx = base+i; if (idx < M) offsets[idx] = tpre + v[i]; }
  if (t == 255) part[blockIdx.x] = tsum[255];
}

__global__ void k_scan2(int* __restrict__ part, int nblk, int* __restrict__ offsets, int M, int E)
{
  __shared__ int tmp[256];
  int t = threadIdx.x;
  int v = (t < nblk) ? part[t] : 0;
  tmp[t] = v;
  __syncthreads();
  for (int d = 1; d < 256; d <<= 1){
    int y = (t >= d) ? tmp[t-d] : 0;
    __syncthreads();
    tmp[t] += y;
    __syncthreads();
  }
  if (t < nblk) part[t] = tmp[t] - v;   // exclusive
  if (t == 0) offsets[M] = E;
}

// ------- pass2: scatter to coarse buckets -------
__global__ __launch_bounds__(256) void k_pass2(
    const int* __restrict__ ei,
    const int* __restrict__ SO, const int* __restrict__ part,
    unsigned* __restrict__ packed,
    int E, int N, int nb1, int nwords)
{
  __shared__ int cur[1024];
  __shared__ int sflag;
  int tid = threadIdx.x;
  int j = blockIdx.x;
  int jm = ((j & 7) << 7) | (j >> 3);
  for (int i = tid; i < nb1; i += 256){
    int idx = i*1024 + jm;
    cur[i] = SO[idx] + part[idx >> 11];
  }
  int is32 = detect_i32(ei, nwords, tid, &sflag);
  for (int e = j*256 + tid; e < E; e += 1024*256){
    int r, c; load_rc32(ei, is32, e, E, N, r, c);
    int bin = c >> 8, low = c & 255;
    int pos = atomicAdd(&cur[bin], 1);
    packed[pos] = ((unsigned)low << 24) | (unsigned)r;
  }
}

// ------- pass3: bucket-local counting sort -> node-major CSR -------
template<typename IT>
__global__ __launch_bounds__(256) void k_pass3(
    const unsigned* __restrict__ packed,
    const int* __restrict__ SO, const int* __restrict__ part,
    int* __restrict__ offC,
    IT* __restrict__ list2,
    int N, int nb1, int M, int E)
{
  __shared__ int hist[256], scn[256], cur[256];
  int tid = threadIdx.x;
  int bin = blockIdx.x;
  int i0 = bin*1024;
  int i1 = (bin+1)*1024;
  int segStart = SO[i0] + part[i0 >> 11];
  int segEnd   = (i1 >= M) ? E : (SO[i1] + part[i1 >> 11]);

  hist[tid] = 0;
  __syncthreads();
  for (int p = segStart + tid; p < segEnd; p += 256)
    atomicAdd(&hist[packed[p] >> 24], 1);
  __syncthreads();
  int own = hist[tid];
  scn[tid] = own;
  __syncthreads();
  for (int d = 1; d < 256; d <<= 1){
    int y = (tid >= d) ? scn[tid-d] : 0;
    __syncthreads();
    scn[tid] += y;
    __syncthreads();
  }
  int excl = scn[tid] - own;
  cur[tid] = excl;
  int node = bin*256 + tid;
  if (node < N) offC[node] = segStart + excl;
  if (bin == nb1-1 && tid == 0) offC[N] = E;
  __syncthreads();
  for (int p = segStart + tid; p < segEnd; p += 256){
    unsigned u = packed[p];
    int pos = atomicAdd(&cur[u >> 24], 1);
    list2[segStart + pos] = (IT)(u & 0xFFFFFFu);
  }
}

// ------- k_aggV: vectorized aggregation with 8-deep gather pipelining -------
template<int VPREC, typename IT>
__global__ __launch_bounds__(256) void k_aggV(
    const unsigned short* __restrict__ uh,  // [N,64] bf16
    const float* vfin, const unsigned short* vhin,
    float* aggf, unsigned short* aggh,
    const float* __restrict__ b1,
    const float* __restrict__ W2,   // [64,64]
    const float* __restrict__ b2,
    const int* __restrict__ offC, const IT* __restrict__ list2, int N)
{
  __shared__ float sS[4][64];
  int tid = threadIdx.x, lane = tid & 63, w = tid >> 6;
  int rsub = lane >> 3, fo = lane & 7;
  float w2c[64];
  #pragma unroll
  for (int j = 0; j < 64; j++) w2c[j] = W2[j*64 + lane];
  float b2l = b2[lane];
  float b1o[8];
  #pragma unroll
  for (int k = 0; k < 8; k++) b1o[k] = b1[fo*8 + k];

  for (int node = blockIdx.x*4 + w; node < N; node += gridDim.x*4){
    int base = offC[node];
    int deg  = offC[node+1] - base;

    float vc8[8];
    #pragma unroll
    for (int k = 0; k < 8; k++)
      vc8[k] = (VPREC ? vfin[(size_t)node*64 + fo*8 + k]
                      : gbf(vhin + (size_t)node*64 + fo*8 + k)) + b1o[k];

    float acc8[8];
    #pragma unroll
    for (int k = 0; k < 8; k++) acc8[k] = 0.f;

    #pragma unroll 1
    for (int cs = 0; cs < deg; cs += 64){
      int clen = min(deg - cs, 64);
      int nbatch = (clen + 7) >> 3;                       // wave-uniform
      int myidx = (lane < clen) ? (int)list2[base + cs + lane] : 0;

      // phase 1: issue ALL batch gathers (up to 8 in flight)
      uint4 d[8];
      #pragma unroll
      for (int b = 0; b < 8; b++){
        if (b < nbatch){
          int ss = min(b*8 + rsub, clen - 1);
          int rr = __shfl(myidx, ss);
          d[b] = *reinterpret_cast<const uint4*>(uh + (size_t)rr*64 + fo*8);
        }
      }
      // phase 2: unpack + accumulate
      #pragma unroll
      for (int b = 0; b < 8; b++){
        if (b < nbatch){
          bool valid = (b*8 + rsub) < clen;
          uint4 dv = d[b];
          float f0 = bflo(dv.x), f1 = bfhi(dv.x), f2 = bflo(dv.y), f3 = bfhi(dv.y);
          float f4 = bflo(dv.z), f5 = bfhi(dv.z), f6 = bflo(dv.w), f7 = bfhi(dv.w);
          float r0 = fmaxf(f0 + vc8[0], 0.f), r1 = fmaxf(f1 + vc8[1], 0.f);
          float r2 = fmaxf(f2 + vc8[2], 0.f), r3 = fmaxf(f3 + vc8[3], 0.f);
          float r4 = fmaxf(f4 + vc8[4], 0.f), r5 = fmaxf(f5 + vc8[5], 0.f);
          float r6 = fmaxf(f6 + vc8[6], 0.f), r7 = fmaxf(f7 + vc8[7], 0.f);
          if (valid){
            acc8[0] += r0; acc8[1] += r1; acc8[2] += r2; acc8[3] += r3;
            acc8[4] += r4; acc8[5] += r5; acc8[6] += r6; acc8[7] += r7;
          }
        }
      }
    }

    #pragma unroll
    for (int m = 8; m < 64; m <<= 1){
      #pragma unroll
      for (int k = 0; k < 8; k++) acc8[k] += __shfl_xor(acc8[k], m);
    }
    float inv = (deg > 0) ? 1.0f/(float)deg : 0.f;
    if (rsub == 0){
      float4 a, b;
      a.x = acc8[0]*inv; a.y = acc8[1]*inv; a.z = acc8[2]*inv; a.w = acc8[3]*inv;
      b.x = acc8[4]*inv; b.y = acc8[5]*inv; b.z = acc8[6]*inv; b.w = acc8[7]*inv;
      float4* sp = reinterpret_cast<float4*>(&sS[w][fo*8]);
      sp[0] = a; sp[1] = b;
    }
    const float4* s4 = reinterpret_cast<const float4*>(&sS[w][0]);
    float m0 = b2l, m1 = 0.f, m2 = 0.f, m3 = 0.f;
    #pragma unroll
    for (int q = 0; q < 16; q += 4){
      float4 v0 = s4[q], v1 = s4[q+1], v2 = s4[q+2], v3 = s4[q+3];
      m0 += v0.x*w2c[4*q+0]  + v0.y*w2c[4*q+1]  + v0.z*w2c[4*q+2]  + v0.w*w2c[4*q+3];
      m1 += v1.x*w2c[4*q+4]  + v1.y*w2c[4*q+5]  + v1.z*w2c[4*q+6]  + v1.w*w2c[4*q+7];
      m2 += v2.x*w2c[4*q+8]  + v2.y*w2c[4*q+9]  + v2.z*w2c[4*q+10] + v2.w*w2c[4*q+11];
      m3 += v3.x*w2c[4*q+12] + v3.y*w2c[4*q+13] + v3.z*w2c[4*q+14] + v3.w*w2c[4*q+15];
    }
    float m = (m0 + m1) + (m2 + m3);
    if (deg == 0) m = 0.f;
    if (VPREC) aggf[(size_t)node*64 + lane] = m;
    else       aggh[(size_t)node*64 + lane] = f2bu(m);
  }
}

// ------- k_updM: MFMA update MLP (R20, unchanged) -------
template<int VPREC>
__global__ __launch_bounds__(256) void k_updM(
    const unsigned short* __restrict__ hb,
    const float* __restrict__ aggf, const unsigned short* __restrict__ aggh,
    const float* __restrict__ uW1, const float* __restrict__ ub1,
    const float* __restrict__ uW2, const float* __restrict__ ub2,
    float* __restrict__ out, int N)
{
  __shared__ unsigned short F_lds[64*136];
  __shared__ unsigned short W1T[64*136];
  __shared__ unsigned short W2T[32*72];
  __shared__ unsigned short S_lds[4][16*72];
  __shared__ float b1s[64], b2s[32];

  int tid = threadIdx.x, lane = tid & 63, w = tid >> 6;
  int gbase = blockIdx.x * 64;

  for (int i = tid; i < 64*128; i += 256){
    int nl = i >> 7, f = i & 127;
    int ng = gbase + nl;
    unsigned short val = 0;
    if (ng < N){
      if (f < 64) val = hb[(size_t)ng*64 + f];
      else        val = VPREC ? f2bu(aggf[(size_t)ng*64 + (f-64)]) : aggh[(size_t)ng*64 + (f-64)];
    }
    F_lds[nl*136 + f] = val;
  }
  for (int i = tid; i < 128*64; i += 256){
    int k = i >> 6, j = i & 63;
    W1T[j*136 + k] = f2bu(uW1[i]);
  }
  for (int i = tid; i < 64*32; i += 256){
    int k = i >> 5, c = i & 31;
    W2T[c*72 + k] = f2bu(uW2[i]);
  }
  if (tid < 64) b1s[tid] = ub1[tid];
  if (tid < 32) b2s[tid] = ub2[tid];
  __syncthreads();

  int r  = lane & 15;
  int kg = lane >> 4;
  int wb = w * 16;

  float4v acc0 = {0.f,0.f,0.f,0.f}, acc1 = acc0, acc2 = acc0, acc3 = acc0;
  #pragma unroll
  for (int kt = 0; kt < 4; kt++){
    short8v a = *reinterpret_cast<const short8v*>(&F_lds[(wb + r)*136 + kt*32 + kg*8]);
    short8v b0 = *reinterpret_cast<const short8v*>(&W1T[( 0 + r)*136 + kt*32 + kg*8]);
    short8v b1v= *reinterpret_cast<const short8v*>(&W1T[(16 + r)*136 + kt*32 + kg*8]);
    short8v b2v= *reinterpret_cast<const short8v*>(&W1T[(32 + r)*136 + kt*32 + kg*8]);
    short8v b3v= *reinterpret_cast<const short8v*>(&W1T[(48 + r)*136 + kt*32 + kg*8]);
    acc0 = __builtin_amdgcn_mfma_f32_16x16x32_bf16(a, b0, acc0, 0, 0, 0);
    acc1 = __builtin_amdgcn_mfma_f32_16x16x32_bf16(a, b1v, acc1, 0, 0, 0);
    acc2 = __builtin_amdgcn_mfma_f32_16x16x32_bf16(a, b2v, acc2, 0, 0, 0);
    acc3 = __builtin_amdgcn_mfma_f32_16x16x32_bf16(a, b3v, acc3, 0, 0, 0);
  }
  {
    float bb0 = b1s[ 0 + r], bb1 = b1s[16 + r], bb2 = b1s[32 + r], bb3 = b1s[48 + r];
    #pragma unroll
    for (int i = 0; i < 4; i++){
      int row = kg*4 + i;
      S_lds[w][row*72 +  0 + r] = f2bu(fmaxf(acc0[i] + bb0, 0.f));
      S_lds[w][row*72 + 16 + r] = f2bu(fmaxf(acc1[i] + bb1, 0.f));
      S_lds[w][row*72 + 32 + r] = f2bu(fmaxf(acc2[i] + bb2, 0.f));
      S_lds[w][row*72 + 48 + r] = f2bu(fmaxf(acc3[i] + bb3, 0.f));
    }
  }

  float4v d0 = {0.f,0.f,0.f,0.f}, d1 = d0;
  #pragma unroll
  for (int kt = 0; kt < 2; kt++){
    short8v a2 = *reinterpret_cast<const short8v*>(&S_lds[w][r*72 + kt*32 + kg*8]);
    short8v c0 = *reinterpret_cast<const short8v*>(&W2T[( 0 + r)*72 + kt*32 + kg*8]);
    short8v c1 = *reinterpret_cast<const short8v*>(&W2T[(16 + r)*72 + kt*32 + kg*8]);
    d0 = __builtin_amdgcn_mfma_f32_16x16x32_bf16(a2, c0, d0, 0, 0, 0);
    d1 = __builtin_amdgcn_mfma_f32_16x16x32_bf16(a2, c1, d1, 0, 0, 0);
  }
  {
    float bb0 = b2s[ 0 + r], bb1 = b2s[16 + r];
    #pragma unroll
    for (int i = 0; i < 4; i++){
      int ng = gbase + wb + kg*4 + i;
      if (ng < N){
        out[(size_t)ng*32 +  0 + r] = d0[i] + bb0;
        out[(size_t)ng*32 + 16 + r] = d1[i] + bb1;
      }
    }
  }
}

// ------- k_tac: thread-per-node tactical head (reads h2 from out) -------
__global__ __launch_bounds__(256) void k_tac(
    const float* __restrict__ tW1, const float* __restrict__ tb1,
    const float* __restrict__ tW2, const float* __restrict__ tb2,
    const float* __restrict__ tW3, const float* __restrict__ tb3,
    float* out, int N)
{
  __shared__ float tW1s[32*64];
  __shared__ float tW2s[64*16];
  __shared__ float tW3s[64];
  __shared__ float tb1s[64], tb2s[16], tb3s[4];
  int tid = threadIdx.x;
  for (int i = tid; i < 32*64; i += 256) tW1s[i] = tW1[i];
  for (int i = tid; i < 64*16; i += 256) tW2s[i] = tW2[i];
  if (tid < 64){ tb1s[tid] = tb1[tid]; tW3s[tid] = tW3[tid]; }
  if (tid < 16) tb2s[tid] = tb2[tid];
  if (tid < 4)  tb3s[tid] = tb3[tid];
  __syncthreads();
  int n = blockIdx.x * 256 + tid;
  if (n >= N) return;

  float h2[32];
  const float4* hp = reinterpret_cast<const float4*>(out + (size_t)n*32);
  #pragma unroll
  for (int q = 0; q < 8; q++){
    float4 v = hp[q];
    h2[4*q+0]=v.x; h2[4*q+1]=v.y; h2[4*q+2]=v.z; h2[4*q+3]=v.w;
  }

  float t2[16];
  #pragma unroll
  for (int m = 0; m < 16; m++) t2[m] = 0.f;
  #pragma unroll 1
  for (int j = 0; j < 64; j++){
    float s = tb1s[j];
    #pragma unroll
    for (int k = 0; k < 32; k++) s += h2[k] * tW1s[k*64 + j];
    s = fmaxf(s, 0.f);
    #pragma unroll
    for (int m = 0; m < 16; m++) t2[m] += s * tW2s[j*16 + m];
  }
  float o[4];
  #pragma unroll
  for (int q = 0; q < 4; q++) o[q] = tb3s[q];
  #pragma unroll
  for (int m = 0; m < 16; m++){
    float tm = fmaxf(t2[m] + tb2s[m], 0.f);
    #pragma unroll
    for (int q = 0; q < 4; q++) o[q] += tm * tW3s[m*4 + q];
  }
  float4* o2 = reinterpret_cast<float4*>(out + (size_t)N*32 + (size_t)n*4);
  float4 vv; vv.x = o[0]; vv.y = o[1]; vv.z = o[2]; vv.w = o[3];
  *o2 = vv;
}

extern "C" void kernel_launch(void* const* d_in, const int* in_sizes, int n_in,
                              void* d_out, int out_size, void* d_ws, size_t ws_size,
                              hipStream_t stream)
{
  const float* x     = (const float*)d_in[0];
  const int*   ei    = (const int*)d_in[1];
  const float* encW1 = (const float*)d_in[2];
  const float* encb1 = (const float*)d_in[3];
  const float* encW2 = (const float*)d_in[4];
  const float* encb2 = (const float*)d_in[5];
  const float* msgW1 = (const float*)d_in[6];
  const float* msgb1 = (const float*)d_in[7];
  const float* msgW2 = (const float*)d_in[8];
  const float* msgb2 = (const float*)d_in[9];
  const float* updW1 = (const float*)d_in[10];
  const float* updb1 = (const float*)d_in[11];
  const float* updW2 = (const float*)d_in[12];
  const float* updb2 = (const float*)d_in[13];
  const float* tacW1 = (const float*)d_in[14];
  const float* tacb1 = (const float*)d_in[15];
  const float* tacW2 = (const float*)d_in[16];
  const float* tacb2 = (const float*)d_in[17];
  const float* tacW3 = (const float*)d_in[18];
  const float* tacb3 = (const float*)d_in[19];

  int N = in_sizes[0] / 6;
  int E = in_sizes[1] / 2;
  float* out = (float*)d_out;
  int idx16 = (N <= 65535) ? 1 : 0;
  int nwords = (2*E < 8192) ? 2*E : 8192;

  int nb1 = (N + 255) >> 8;            // 196 for N=50k
  const int G1 = 1024;                 // jm hardcodes 1024
  int M   = nb1 * G1;

  auto align = [](size_t v){ return (v + 255) & ~(size_t)255; };
  size_t hbB = (size_t)N*64*2, uhB = (size_t)N*64*2;
  size_t list2B = (size_t)E * (idx16 ? 2 : 4);
  auto tail = [&](size_t o){
    o = align(o); o += (size_t)M*4;          // BH
    o = align(o); o += (size_t)(M+1)*4;      // SO
    o = align(o); o += 256*4;                // part
    o = align(o); o += (size_t)(N+1)*4;      // offC
    o = align(o); o += list2B;               // list2
    return o;
  };
  size_t total2 = tail(align(align(hbB) + uhB) + (size_t)N*64*4);
  int VPREC = (ws_size >= total2) ? 1 : 0;

  char* ws = (char*)d_ws;
  size_t o = 0;
  unsigned short* hb = (unsigned short*)(ws + o); o = align(o + hbB);
  unsigned short* uh = (unsigned short*)(ws + o); o = align(o + uhB);
  float* vf = nullptr; unsigned short* vh = nullptr;
  if (VPREC){ vf = (float*)(ws + o);          o = align(o + (size_t)N*64*4); }
  else      { vh = (unsigned short*)(ws + o); o = align(o + (size_t)N*64*2); }
  int* BH   = (int*)(ws + o); o = align(o + (size_t)M*4);
  int* SO   = (int*)(ws + o); o = align(o + (size_t)(M+1)*4);
  int* part = (int*)(ws + o); o = align(o + 256*4);
  int* offC = (int*)(ws + o); o = align(o + (size_t)(N+1)*4);
  void* list2P = (void*)(ws + o); o = align(o + list2B);
  unsigned* packed = (unsigned*)out;   // d_out scratch; dead before k_updM

  dim3 blk(256);
  int nblkN  = (N + 255) / 256;        // 196
  int nblkU  = (N + 63) / 64;          // 782 (MFMA blocks)
  int nblkS1 = (M + 2047) / 2048;      // 98 (<=256 req by k_scan2)

  if (VPREC) k_encM<1><<<dim3(nblkU), blk, 0, stream>>>(x, encW1, encb1, encW2, encb2, msgW1,
                                                        hb, uh, vf, vh, N);
  else       k_encM<0><<<dim3(nblkU), blk, 0, stream>>>(x, encW1, encb1, encW2, encb2, msgW1,
                                                        hb, uh, vf, vh, N);
  k_hist<<<dim3(G1), blk, 0, stream>>>(ei, BH, E, N, nb1, nwords);
  k_scan1<<<dim3(nblkS1), blk, 0, stream>>>(BH, SO, part, M);
  k_scan2<<<dim3(1),      blk, 0, stream>>>(part, nblkS1, SO, M, E);
  k_pass2<<<dim3(G1),     blk, 0, stream>>>(ei, SO, part, packed, E, N, nb1, nwords);
  if (idx16){
    k_pass3<unsigned short><<<dim3(nb1), blk, 0, stream>>>(packed, SO, part, offC, (unsigned short*)list2P, N, nb1, M, E);
    if (VPREC) k_aggV<1,unsigned short><<<dim3(2048), blk, 0, stream>>>(uh, vf, vh, vf, vh, msgb1, msgW2, msgb2, offC, (unsigned short*)list2P, N);
    else       k_aggV<0,unsigned short><<<dim3(2048), blk, 0, stream>>>(uh, vf, vh, vf, vh, msgb1, msgW2, msgb2, offC, (unsigned short*)list2P, N);
  } else {
    k_pass3<int><<<dim3(nb1), blk, 0, stream>>>(packed, SO, part, offC, (int*)list2P, N, nb1, M, E);
    if (VPREC) k_aggV<1,int><<<dim3(2048), blk, 0, stream>>>(uh, vf, vh, vf, vh, msgb1, msgW2, msgb2, offC, (int*)list2P, N);
    else       k_aggV<0,int><<<dim3(2048), blk, 0, stream>>>(uh, vf, vh, vf, vh, msgb1, msgW2, msgb2, offC, (int*)list2P, N);
  }
  if (VPREC) k_updM<1><<<dim3(nblkU), blk, 0, stream>>>(hb, vf, vh, updW1, updb1, updW2, updb2, out, N);
  else       k_updM<0><<<dim3(nblkU), blk, 0, stream>>>(hb, vf, vh, updW1, updb1, updW2, updb2, out, N);
  k_tac<<<dim3(nblkN), blk, 0, stream>>>(tacW1, tacb1, tacW2, tacb2, tacW3, tacb3, out, N);
}

// Round 23
// 189.553 us; speedup vs baseline: 1.0779x; 1.0779x over previous
//
#include <hip/hip_runtime.h>
#include <hip/hip_bf16.h>

// BasketballGNN R23: revert aggV to R21 body (VGPR 64 / 8 waves/SIMD) + grid 4096
// for tail-balance. R22 evidence: 8-deep gather pipeline cost +20 VGPR -> 6 waves/SIMD
// (occ 26%), regressed 59->76us. Occupancy > register-ILP in this latency-bound kernel.

__device__ inline float bflo(unsigned u){ return __uint_as_float(u << 16); }
__device__ inline float bfhi(unsigned u){ return __uint_as_float(u & 0xffff0000u); }
__device__ inline float gbf(const unsigned short* p){ return __uint_as_float(((unsigned)(*p)) << 16); }
__device__ inline unsigned short f2bu(float f){
  unsigned x = __float_as_uint(f);
  unsigned r = (x + 0x7fffu + ((x >> 16) & 1u)) >> 16;  // RNE
  return (unsigned short)r;
}

typedef __attribute__((ext_vector_type(8))) short short8v;
typedef __attribute__((ext_vector_type(4))) float float4v;

// detect edge-index width (int64 -> odd 32b words all zero). 1 = int32, 0 = int64.
__device__ inline int detect_i32(const int* ei, int nwords, int tid, int* sflag){
  if (tid == 0) *sflag = 0;
  __syncthreads();
  int acc = 0;
  for (int i = tid; i < nwords; i += 256)
    if (i & 1) acc |= ei[i];
  if (acc) atomicOr(sflag, 1);
  __syncthreads();
  return *sflag;
}

__device__ inline void load_rc32(const int* ei, int is32, int e, int E, int N, int& r, int& c){
  if (is32){ r = ei[e]; c = ei[(size_t)E + e]; }
  else     { r = ei[2*(size_t)e]; c = ei[2*((size_t)E + (size_t)e)]; }
  r = min(max(r, 0), N-1); c = min(max(c, 0), N-1);
}

// ------- k_encM: MFMA encoder + u,v (R21, unchanged) -------
template<int VPREC>
__global__ __launch_bounds__(256) void k_encM(
    const float* __restrict__ x,    // [N,6]
    const float* __restrict__ eW1, const float* __restrict__ eb1,
    const float* __restrict__ eW2, const float* __restrict__ eb2,
    const float* __restrict__ mW1,  // [128,64]
    unsigned short* __restrict__ hb,
    unsigned short* __restrict__ uh,
    float* __restrict__ vf, unsigned short* __restrict__ vh,
    int N)
{
  __shared__ unsigned short F_lds[64*40];
  __shared__ unsigned short W1T[64*40];
  __shared__ unsigned short W2T[64*72];
  __shared__ unsigned short loT[64*72];
  __shared__ unsigned short hiT[64*72];
  __shared__ unsigned short S_lds[4][16*72];
  __shared__ float b1s[64], b2s[64];

  int tid = threadIdx.x, lane = tid & 63, w = tid >> 6;
  int gbase = blockIdx.x * 64;

  for (int i = tid; i < 64*40; i += 256){
    int nl = i / 40, k = i % 40;
    int ng = gbase + nl;
    unsigned short val = 0;
    if (ng < N && k < 6) val = f2bu(x[(size_t)ng*6 + k]);
    F_lds[i] = val;
  }
  for (int i = tid; i < 64*40; i += 256){
    int j = i / 40, k = i % 40;
    W1T[i] = (k < 6) ? f2bu(eW1[k*64 + j]) : (unsigned short)0;
  }
  for (int i = tid; i < 64*64; i += 256){
    int k = i >> 6, c = i & 63;
    W2T[c*72 + k] = f2bu(eW2[i]);
    loT[c*72 + k] = f2bu(mW1[i]);
    hiT[c*72 + k] = f2bu(mW1[64*64 + i]);
  }
  if (tid < 64){ b1s[tid] = eb1[tid]; b2s[tid] = eb2[tid]; }
  __syncthreads();

  int r  = lane & 15;
  int kg = lane >> 4;
  int wb = w * 16;

  {
    short8v a = *reinterpret_cast<const short8v*>(&F_lds[(wb + r)*40 + kg*8]);
    float4v c0 = {0.f,0.f,0.f,0.f}, c1 = c0, c2 = c0, c3 = c0;
    short8v b0 = *reinterpret_cast<const short8v*>(&W1T[( 0 + r)*40 + kg*8]);
    short8v b1v= *reinterpret_cast<const short8v*>(&W1T[(16 + r)*40 + kg*8]);
    short8v b2v= *reinterpret_cast<const short8v*>(&W1T[(32 + r)*40 + kg*8]);
    short8v b3v= *reinterpret_cast<const short8v*>(&W1T[(48 + r)*40 + kg*8]);
    c0 = __builtin_amdgcn_mfma_f32_16x16x32_bf16(a, b0, c0, 0, 0, 0);
    c1 = __builtin_amdgcn_mfma_f32_16x16x32_bf16(a, b1v, c1, 0, 0, 0);
    c2 = __builtin_amdgcn_mfma_f32_16x16x32_bf16(a, b2v, c2, 0, 0, 0);
    c3 = __builtin_amdgcn_mfma_f32_16x16x32_bf16(a, b3v, c3, 0, 0, 0);
    float bb0 = b1s[ 0 + r], bb1 = b1s[16 + r], bb2 = b1s[32 + r], bb3 = b1s[48 + r];
    #pragma unroll
    for (int i = 0; i < 4; i++){
      int row = kg*4 + i;
      S_lds[w][row*72 +  0 + r] = f2bu(fmaxf(c0[i] + bb0, 0.f));
      S_lds[w][row*72 + 16 + r] = f2bu(fmaxf(c1[i] + bb1, 0.f));
      S_lds[w][row*72 + 32 + r] = f2bu(fmaxf(c2[i] + bb2, 0.f));
      S_lds[w][row*72 + 48 + r] = f2bu(fmaxf(c3[i] + bb3, 0.f));
    }
  }

  float hv[4][4];
  {
    float4v c0 = {0.f,0.f,0.f,0.f}, c1 = c0, c2 = c0, c3 = c0;
    #pragma unroll
    for (int kt = 0; kt < 2; kt++){
      short8v a2 = *reinterpret_cast<const short8v*>(&S_lds[w][r*72 + kt*32 + kg*8]);
      short8v d0 = *reinterpret_cast<const short8v*>(&W2T[( 0 + r)*72 + kt*32 + kg*8]);
      short8v d1 = *reinterpret_cast<const short8v*>(&W2T[(16 + r)*72 + kt*32 + kg*8]);
      short8v d2 = *reinterpret_cast<const short8v*>(&W2T[(32 + r)*72 + kt*32 + kg*8]);
      short8v d3 = *reinterpret_cast<const short8v*>(&W2T[(48 + r)*72 + kt*32 + kg*8]);
      c0 = __builtin_amdgcn_mfma_f32_16x16x32_bf16(a2, d0, c0, 0, 0, 0);
      c1 = __builtin_amdgcn_mfma_f32_16x16x32_bf16(a2, d1, c1, 0, 0, 0);
      c2 = __builtin_amdgcn_mfma_f32_16x16x32_bf16(a2, d2, c2, 0, 0, 0);
      c3 = __builtin_amdgcn_mfma_f32_16x16x32_bf16(a2, d3, c3, 0, 0, 0);
    }
    float bb0 = b2s[ 0 + r], bb1 = b2s[16 + r], bb2 = b2s[32 + r], bb3 = b2s[48 + r];
    #pragma unroll
    for (int i = 0; i < 4; i++){
      hv[0][i] = c0[i] + bb0; hv[1][i] = c1[i] + bb1;
      hv[2][i] = c2[i] + bb2; hv[3][i] = c3[i] + bb3;
    }
  }
  #pragma unroll
  for (int i = 0; i < 4; i++){
    int row = kg*4 + i;
    int ng = gbase + wb + row;
    unsigned short h0 = f2bu(hv[0][i]), h1 = f2bu(hv[1][i]);
    unsigned short h2 = f2bu(hv[2][i]), h3 = f2bu(hv[3][i]);
    if (ng < N){
      hb[(size_t)ng*64 +  0 + r] = h0;
      hb[(size_t)ng*64 + 16 + r] = h1;
      hb[(size_t)ng*64 + 32 + r] = h2;
      hb[(size_t)ng*64 + 48 + r] = h3;
    }
    S_lds[w][row*72 +  0 + r] = h0;
    S_lds[w][row*72 + 16 + r] = h1;
    S_lds[w][row*72 + 32 + r] = h2;
    S_lds[w][row*72 + 48 + r] = h3;
  }

  float4v u0 = {0.f,0.f,0.f,0.f}, u1 = u0, u2 = u0, u3 = u0;
  float4v v0 = u0, v1 = u0, v2 = u0, v3 = u0;
  #pragma unroll
  for (int kt = 0; kt < 2; kt++){
    short8v a3 = *reinterpret_cast<const short8v*>(&S_lds[w][r*72 + kt*32 + kg*8]);
    short8v l0 = *reinterpret_cast<const short8v*>(&loT[( 0 + r)*72 + kt*32 + kg*8]);
    short8v l1 = *reinterpret_cast<const short8v*>(&loT[(16 + r)*72 + kt*32 + kg*8]);
    short8v l2 = *reinterpret_cast<const short8v*>(&loT[(32 + r)*72 + kt*32 + kg*8]);
    short8v l3 = *reinterpret_cast<const short8v*>(&loT[(48 + r)*72 + kt*32 + kg*8]);
    short8v g0 = *reinterpret_cast<const short8v*>(&hiT[( 0 + r)*72 + kt*32 + kg*8]);
    short8v g1 = *reinterpret_cast<const short8v*>(&hiT[(16 + r)*72 + kt*32 + kg*8]);
    short8v g2 = *reinterpret_cast<const short8v*>(&hiT[(32 + r)*72 + kt*32 + kg*8]);
    short8v g3 = *reinterpret_cast<const short8v*>(&hiT[(48 + r)*72 + kt*32 + kg*8]);
    u0 = __builtin_amdgcn_mfma_f32_16x16x32_bf16(a3, l0, u0, 0, 0, 0);
    u1 = __builtin_amdgcn_mfma_f32_16x16x32_bf16(a3, l1, u1, 0, 0, 0);
    u2 = __builtin_amdgcn_mfma_f32_16x16x32_bf16(a3, l2, u2, 0, 0, 0);
    u3 = __builtin_amdgcn_mfma_f32_16x16x32_bf16(a3, l3, u3, 0, 0, 0);
    v0 = __builtin_amdgcn_mfma_f32_16x16x32_bf16(a3, g0, v0, 0, 0, 0);
    v1 = __builtin_amdgcn_mfma_f32_16x16x32_bf16(a3, g1, v1, 0, 0, 0);
    v2 = __builtin_amdgcn_mfma_f32_16x16x32_bf16(a3, g2, v2, 0, 0, 0);
    v3 = __builtin_amdgcn_mfma_f32_16x16x32_bf16(a3, g3, v3, 0, 0, 0);
  }
  #pragma unroll
  for (int i = 0; i < 4; i++){
    int ng = gbase + wb + kg*4 + i;
    if (ng < N){
      uh[(size_t)ng*64 +  0 + r] = f2bu(u0[i]);
      uh[(size_t)ng*64 + 16 + r] = f2bu(u1[i]);
      uh[(size_t)ng*64 + 32 + r] = f2bu(u2[i]);
      uh[(size_t)ng*64 + 48 + r] = f2bu(u3[i]);
      if (VPREC){
        vf[(size_t)ng*64 +  0 + r] = v0[i];
        vf[(size_t)ng*64 + 16 + r] = v1[i];
        vf[(size_t)ng*64 + 32 + r] = v2[i];
        vf[(size_t)ng*64 + 48 + r] = v3[i];
      } else {
        vh[(size_t)ng*64 +  0 + r] = f2bu(v0[i]);
        vh[(size_t)ng*64 + 16 + r] = f2bu(v1[i]);
        vh[(size_t)ng*64 + 32 + r] = f2bu(v2[i]);
        vh[(size_t)ng*64 + 48 + r] = f2bu(v3[i]);
      }
    }
  }
}

// ------- k_hist: coarse histogram (R14, unchanged) -------
__global__ __launch_bounds__(256) void k_hist(
    const int* __restrict__ ei,
    int* __restrict__ BH,
    int E, int N, int nb1, int nwords)
{
  __shared__ int hist[1024];
  __shared__ int sflag;
  int tid = threadIdx.x;
  for (int i = tid; i < nb1; i += 256) hist[i] = 0;
  int is32 = detect_i32(ei, nwords, tid, &sflag);
  int j = blockIdx.x;
  for (int e = j*256 + tid; e < E; e += 1024*256){
    int c = is32 ? ei[(size_t)E + e] : ei[2*((size_t)E + (size_t)e)];
    c = min(max(c, 0), N-1);
    atomicAdd(&hist[c >> 8], 1);
  }
  __syncthreads();
  int jm = ((j & 7) << 7) | (j >> 3);
  for (int i = tid; i < nb1; i += 256) BH[(size_t)i*1024 + jm] = hist[i];
}

// ---------------- scans ----------------
__global__ void k_scan1(const int* __restrict__ counts, int* __restrict__ offsets,
                        int* __restrict__ part, int M)
{
  __shared__ int tsum[256];
  int t = threadIdx.x;
  int base = blockIdx.x*2048 + t*8;
  int v[8]; int s = 0;
  #pragma unroll
  for (int i = 0; i < 8; i++){ int idx = base+i; v[i] = (idx < M) ? counts[idx] : 0; }
  #pragma unroll
  for (int i = 0; i < 8; i++){ int t0 = v[i]; v[i] = s; s += t0; }
  tsum[t] = s;
  __syncthreads();
  for (int d = 1; d < 256; d <<= 1){
    int y = (t >= d) ? tsum[t-d] : 0;
    __syncthreads();
    tsum[t] += y;
    __syncthreads();
  }
  int tpre = tsum[t] - s;
  #pragma unroll
  for (int i = 0; i < 8; i++){ int idx = base+i; if (idx < M) offsets[idx] = tpre + v[i]; }
  if (t == 255) part[blockIdx.x] = tsum[255];
}

__global__ void k_scan2(int* __restrict__ part, int nblk, int* __restrict__ offsets, int M, int E)
{
  __shared__ int tmp[256];
  int t = threadIdx.x;
  int v = (t < nblk) ? part[t] : 0;
  tmp[t] = v;
  __syncthreads();
  for (int d = 1; d < 256; d <<= 1){
    int y = (t >= d) ? tmp[t-d] : 0;
    __syncthreads();
    tmp[t] += y;
    __syncthreads();
  }
  if (t < nblk) part[t] = tmp[t] - v;   // exclusive
  if (t == 0) offsets[M] = E;
}

// ------- pass2: scatter to coarse buckets -------
__global__ __launch_bounds__(256) void k_pass2(
    const int* __restrict__ ei,
    const int* __restrict__ SO, const int* __restrict__ part,
    unsigned* __restrict__ packed,
    int E, int N, int nb1, int nwords)
{
  __shared__ int cur[1024];
  __shared__ int sflag;
  int tid = threadIdx.x;
  int j = blockIdx.x;
  int jm = ((j & 7) << 7) | (j >> 3);
  for (int i = tid; i < nb1; i += 256){
    int idx = i*1024 + jm;
    cur[i] = SO[idx] + part[idx >> 11];
  }
  int is32 = detect_i32(ei, nwords, tid, &sflag);
  for (int e = j*256 + tid; e < E; e += 1024*256){
    int r, c; load_rc32(ei, is32, e, E, N, r, c);
    int bin = c >> 8, low = c & 255;
    int pos = atomicAdd(&cur[bin], 1);
    packed[pos] = ((unsigned)low << 24) | (unsigned)r;
  }
}

// ------- pass3: bucket-local counting sort -> node-major CSR -------
template<typename IT>
__global__ __launch_bounds__(256) void k_pass3(
    const unsigned* __restrict__ packed,
    const int* __restrict__ SO, const int* __restrict__ part,
    int* __restrict__ offC,
    IT* __restrict__ list2,
    int N, int nb1, int M, int E)
{
  __shared__ int hist[256], scn[256], cur[256];
  int tid = threadIdx.x;
  int bin = blockIdx.x;
  int i0 = bin*1024;
  int i1 = (bin+1)*1024;
  int segStart = SO[i0] + part[i0 >> 11];
  int segEnd   = (i1 >= M) ? E : (SO[i1] + part[i1 >> 11]);

  hist[tid] = 0;
  __syncthreads();
  for (int p = segStart + tid; p < segEnd; p += 256)
    atomicAdd(&hist[packed[p] >> 24], 1);
  __syncthreads();
  int own = hist[tid];
  scn[tid] = own;
  __syncthreads();
  for (int d = 1; d < 256; d <<= 1){
    int y = (tid >= d) ? scn[tid-d] : 0;
    __syncthreads();
    scn[tid] += y;
    __syncthreads();
  }
  int excl = scn[tid] - own;
  cur[tid] = excl;
  int node = bin*256 + tid;
  if (node < N) offC[node] = segStart + excl;
  if (bin == nb1-1 && tid == 0) offC[N] = E;
  __syncthreads();
  for (int p = segStart + tid; p < segEnd; p += 256){
    unsigned u = packed[p];
    int pos = atomicAdd(&cur[u >> 24], 1);
    list2[segStart + pos] = (IT)(u & 0xFFFFFFu);
  }
}

// ------- k_aggV: vectorized aggregation (R21 body; grid 4096 for tail balance) -------
template<int VPREC, typename IT>
__global__ __launch_bounds__(256) void k_aggV(
    const unsigned short* __restrict__ uh,  // [N,64] bf16
    const float* vfin, const unsigned short* vhin,
    float* aggf, unsigned short* aggh,
    const float* __restrict__ b1,
    const float* __restrict__ W2,   // [64,64]
    const float* __restrict__ b2,
    const int* __restrict__ offC, const IT* __restrict__ list2, int N)
{
  __shared__ float sS[4][64];
  int tid = threadIdx.x, lane = tid & 63, w = tid >> 6;
  int rsub = lane >> 3, fo = lane & 7;
  float w2c[64];
  #pragma unroll
  for (int j = 0; j < 64; j++) w2c[j] = W2[j*64 + lane];
  float b2l = b2[lane];
  float b1o[8];
  #pragma unroll
  for (int k = 0; k < 8; k++) b1o[k] = b1[fo*8 + k];

  for (int node = blockIdx.x*4 + w; node < N; node += gridDim.x*4){
    int base = offC[node];
    int deg  = offC[node+1] - base;

    float vc8[8];
    #pragma unroll
    for (int k = 0; k < 8; k++)
      vc8[k] = (VPREC ? vfin[(size_t)node*64 + fo*8 + k]
                      : gbf(vhin + (size_t)node*64 + fo*8 + k)) + b1o[k];

    float acc8[8];
    #pragma unroll
    for (int k = 0; k < 8; k++) acc8[k] = 0.f;

    #pragma unroll 1
    for (int cs = 0; cs < deg; cs += 64){
      int clen = min(deg - cs, 64);
      int myidx = (lane < clen) ? (int)list2[base + cs + lane] : 0;
      #pragma unroll 1
      for (int s = 0; s < clen; s += 8){
        int ss = min(s + rsub, clen - 1);
        int r  = __shfl(myidx, ss);
        bool valid = (s + rsub) < clen;
        const uint4* up = reinterpret_cast<const uint4*>(uh + (size_t)r*64 + fo*8);
        uint4 d = *up;
        float f0 = bflo(d.x), f1 = bfhi(d.x), f2 = bflo(d.y), f3 = bfhi(d.y);
        float f4 = bflo(d.z), f5 = bfhi(d.z), f6 = bflo(d.w), f7 = bfhi(d.w);
        float r0 = fmaxf(f0 + vc8[0], 0.f), r1 = fmaxf(f1 + vc8[1], 0.f);
        float r2 = fmaxf(f2 + vc8[2], 0.f), r3 = fmaxf(f3 + vc8[3], 0.f);
        float r4 = fmaxf(f4 + vc8[4], 0.f), r5 = fmaxf(f5 + vc8[5], 0.f);
        float r6 = fmaxf(f6 + vc8[6], 0.f), r7 = fmaxf(f7 + vc8[7], 0.f);
        if (valid){
          acc8[0] += r0; acc8[1] += r1; acc8[2] += r2; acc8[3] += r3;
          acc8[4] += r4; acc8[5] += r5; acc8[6] += r6; acc8[7] += r7;
        }
      }
    }

    #pragma unroll
    for (int m = 8; m < 64; m <<= 1){
      #pragma unroll
      for (int k = 0; k < 8; k++) acc8[k] += __shfl_xor(acc8[k], m);
    }
    float inv = (deg > 0) ? 1.0f/(float)deg : 0.f;
    if (rsub == 0){
      float4 a, b;
      a.x = acc8[0]*inv; a.y = acc8[1]*inv; a.z = acc8[2]*inv; a.w = acc8[3]*inv;
      b.x = acc8[4]*inv; b.y = acc8[5]*inv; b.z = acc8[6]*inv; b.w = acc8[7]*inv;
      float4* sp = reinterpret_cast<float4*>(&sS[w][fo*8]);
      sp[0] = a; sp[1] = b;
    }
    const float4* s4 = reinterpret_cast<const float4*>(&sS[w][0]);
    float m0 = b2l, m1 = 0.f, m2 = 0.f, m3 = 0.f;
    #pragma unroll
    for (int q = 0; q < 16; q += 4){
      float4 v0 = s4[q], v1 = s4[q+1], v2 = s4[q+2], v3 = s4[q+3];
      m0 += v0.x*w2c[4*q+0]  + v0.y*w2c[4*q+1]  + v0.z*w2c[4*q+2]  + v0.w*w2c[4*q+3];
      m1 += v1.x*w2c[4*q+4]  + v1.y*w2c[4*q+5]  + v1.z*w2c[4*q+6]  + v1.w*w2c[4*q+7];
      m2 += v2.x*w2c[4*q+8]  + v2.y*w2c[4*q+9]  + v2.z*w2c[4*q+10] + v2.w*w2c[4*q+11];
      m3 += v3.x*w2c[4*q+12] + v3.y*w2c[4*q+13] + v3.z*w2c[4*q+14] + v3.w*w2c[4*q+15];
    }
    float m = (m0 + m1) + (m2 + m3);
    if (deg == 0) m = 0.f;
    if (VPREC) aggf[(size_t)node*64 + lane] = m;
    else       aggh[(size_t)node*64 + lane] = f2bu(m);
  }
}

// ------- k_updM: MFMA update MLP (R20, unchanged) -------
template<int VPREC>
__global__ __launch_bounds__(256) void k_updM(
    const unsigned short* __restrict__ hb,
    const float* __restrict__ aggf, const unsigned short* __restrict__ aggh,
    const float* __restrict__ uW1, const float* __restrict__ ub1,
    const float* __restrict__ uW2, const float* __restrict__ ub2,
    float* __restrict__ out, int N)
{
  __shared__ unsigned short F_lds[64*136];
  __shared__ unsigned short W1T[64*136];
  __shared__ unsigned short W2T[32*72];
  __shared__ unsigned short S_lds[4][16*72];
  __shared__ float b1s[64], b2s[32];

  int tid = threadIdx.x, lane = tid & 63, w = tid >> 6;
  int gbase = blockIdx.x * 64;

  for (int i = tid; i < 64*128; i += 256){
    int nl = i >> 7, f = i & 127;
    int ng = gbase + nl;
    unsigned short val = 0;
    if (ng < N){
      if (f < 64) val = hb[(size_t)ng*64 + f];
      else        val = VPREC ? f2bu(aggf[(size_t)ng*64 + (f-64)]) : aggh[(size_t)ng*64 + (f-64)];
    }
    F_lds[nl*136 + f] = val;
  }
  for (int i = tid; i < 128*64; i += 256){
    int k = i >> 6, j = i & 63;
    W1T[j*136 + k] = f2bu(uW1[i]);
  }
  for (int i = tid; i < 64*32; i += 256){
    int k = i >> 5, c = i & 31;
    W2T[c*72 + k] = f2bu(uW2[i]);
  }
  if (tid < 64) b1s[tid] = ub1[tid];
  if (tid < 32) b2s[tid] = ub2[tid];
  __syncthreads();

  int r  = lane & 15;
  int kg = lane >> 4;
  int wb = w * 16;

  float4v acc0 = {0.f,0.f,0.f,0.f}, acc1 = acc0, acc2 = acc0, acc3 = acc0;
  #pragma unroll
  for (int kt = 0; kt < 4; kt++){
    short8v a = *reinterpret_cast<const short8v*>(&F_lds[(wb + r)*136 + kt*32 + kg*8]);
    short8v b0 = *reinterpret_cast<const short8v*>(&W1T[( 0 + r)*136 + kt*32 + kg*8]);
    short8v b1v= *reinterpret_cast<const short8v*>(&W1T[(16 + r)*136 + kt*32 + kg*8]);
    short8v b2v= *reinterpret_cast<const short8v*>(&W1T[(32 + r)*136 + kt*32 + kg*8]);
    short8v b3v= *reinterpret_cast<const short8v*>(&W1T[(48 + r)*136 + kt*32 + kg*8]);
    acc0 = __builtin_amdgcn_mfma_f32_16x16x32_bf16(a, b0, acc0, 0, 0, 0);
    acc1 = __builtin_amdgcn_mfma_f32_16x16x32_bf16(a, b1v, acc1, 0, 0, 0);
    acc2 = __builtin_amdgcn_mfma_f32_16x16x32_bf16(a, b2v, acc2, 0, 0, 0);
    acc3 = __builtin_amdgcn_mfma_f32_16x16x32_bf16(a, b3v, acc3, 0, 0, 0);
  }
  {
    float bb0 = b1s[ 0 + r], bb1 = b1s[16 + r], bb2 = b1s[32 + r], bb3 = b1s[48 + r];
    #pragma unroll
    for (int i = 0; i < 4; i++){
      int row = kg*4 + i;
      S_lds[w][row*72 +  0 + r] = f2bu(fmaxf(acc0[i] + bb0, 0.f));
      S_lds[w][row*72 + 16 + r] = f2bu(fmaxf(acc1[i] + bb1, 0.f));
      S_lds[w][row*72 + 32 + r] = f2bu(fmaxf(acc2[i] + bb2, 0.f));
      S_lds[w][row*72 + 48 + r] = f2bu(fmaxf(acc3[i] + bb3, 0.f));
    }
  }

  float4v d0 = {0.f,0.f,0.f,0.f}, d1 = d0;
  #pragma unroll
  for (int kt = 0; kt < 2; kt++){
    short8v a2 = *reinterpret_cast<const short8v*>(&S_lds[w][r*72 + kt*32 + kg*8]);
    short8v c0 = *reinterpret_cast<const short8v*>(&W2T[( 0 + r)*72 + kt*32 + kg*8]);
    short8v c1 = *reinterpret_cast<const short8v*>(&W2T[(16 + r)*72 + kt*32 + kg*8]);
    d0 = __builtin_amdgcn_mfma_f32_16x16x32_bf16(a2, c0, d0, 0, 0, 0);
    d1 = __builtin_amdgcn_mfma_f32_16x16x32_bf16(a2, c1, d1, 0, 0, 0);
  }
  {
    float bb0 = b2s[ 0 + r], bb1 = b2s[16 + r];
    #pragma unroll
    for (int i = 0; i < 4; i++){
      int ng = gbase + wb + kg*4 + i;
      if (ng < N){
        out[(size_t)ng*32 +  0 + r] = d0[i] + bb0;
        out[(size_t)ng*32 + 16 + r] = d1[i] + bb1;
      }
    }
  }
}

// ------- k_tac: thread-per-node tactical head (reads h2 from out) -------
__global__ __launch_bounds__(256) void k_tac(
    const float* __restrict__ tW1, const float* __restrict__ tb1,
    const float* __restrict__ tW2, const float* __restrict__ tb2,
    const float* __restrict__ tW3, const float* __restrict__ tb3,
    float* out, int N)
{
  __shared__ float tW1s[32*64];
  __shared__ float tW2s[64*16];
  __shared__ float tW3s[64];
  __shared__ float tb1s[64], tb2s[16], tb3s[4];
  int tid = threadIdx.x;
  for (int i = tid; i < 32*64; i += 256) tW1s[i] = tW1[i];
  for (int i = tid; i < 64*16; i += 256) tW2s[i] = tW2[i];
  if (tid < 64){ tb1s[tid] = tb1[tid]; tW3s[tid] = tW3[tid]; }
  if (tid < 16) tb2s[tid] = tb2[tid];
  if (tid < 4)  tb3s[tid] = tb3[tid];
  __syncthreads();
  int n = blockIdx.x * 256 + tid;
  if (n >= N) return;

  float h2[32];
  const float4* hp = reinterpret_cast<const float4*>(out + (size_t)n*32);
  #pragma unroll
  for (int q = 0; q < 8; q++){
    float4 v = hp[q];
    h2[4*q+0]=v.x; h2[4*q+1]=v.y; h2[4*q+2]=v.z; h2[4*q+3]=v.w;
  }

  float t2[16];
  #pragma unroll
  for (int m = 0; m < 16; m++) t2[m] = 0.f;
  #pragma unroll 1
  for (int j = 0; j < 64; j++){
    float s = tb1s[j];
    #pragma unroll
    for (int k = 0; k < 32; k++) s += h2[k] * tW1s[k*64 + j];
    s = fmaxf(s, 0.f);
    #pragma unroll
    for (int m = 0; m < 16; m++) t2[m] += s * tW2s[j*16 + m];
  }
  float o[4];
  #pragma unroll
  for (int q = 0; q < 4; q++) o[q] = tb3s[q];
  #pragma unroll
  for (int m = 0; m < 16; m++){
    float tm = fmaxf(t2[m] + tb2s[m], 0.f);
    #pragma unroll
    for (int q = 0; q < 4; q++) o[q] += tm * tW3s[m*4 + q];
  }
  float4* o2 = reinterpret_cast<float4*>(out + (size_t)N*32 + (size_t)n*4);
  float4 vv; vv.x = o[0]; vv.y = o[1]; vv.z = o[2]; vv.w = o[3];
  *o2 = vv;
}

extern "C" void kernel_launch(void* const* d_in, const int* in_sizes, int n_in,
                              void* d_out, int out_size, void* d_ws, size_t ws_size,
                              hipStream_t stream)
{
  const float* x     = (const float*)d_in[0];
  const int*   ei    = (const int*)d_in[1];
  const float* encW1 = (const float*)d_in[2];
  const float* encb1 = (const float*)d_in[3];
  const float* encW2 = (const float*)d_in[4];
  const float* encb2 = (const float*)d_in[5];
  const float* msgW1 = (const float*)d_in[6];
  const float* msgb1 = (const float*)d_in[7];
  const float* msgW2 = (const float*)d_in[8];
  const float* msgb2 = (const float*)d_in[9];
  const float* updW1 = (const float*)d_in[10];
  const float* updb1 = (const float*)d_in[11];
  const float* updW2 = (const float*)d_in[12];
  const float* updb2 = (const float*)d_in[13];
  const float* tacW1 = (const float*)d_in[14];
  const float* tacb1 = (const float*)d_in[15];
  const float* tacW2 = (const float*)d_in[16];
  const float* tacb2 = (const float*)d_in[17];
  const float* tacW3 = (const float*)d_in[18];
  const float* tacb3 = (const float*)d_in[19];

  int N = in_sizes[0] / 6;
  int E = in_sizes[1] / 2;
  float* out = (float*)d_out;
  int idx16 = (N <= 65535) ? 1 : 0;
  int nwords = (2*E < 8192) ? 2*E : 8192;

  int nb1 = (N + 255) >> 8;            // 196 for N=50k
  const int G1 = 1024;                 // jm hardcodes 1024
  int M   = nb1 * G1;

  auto align = [](size_t v){ return (v + 255) & ~(size_t)255; };
  size_t hbB = (size_t)N*64*2, uhB = (size_t)N*64*2;
  size_t list2B = (size_t)E * (idx16 ? 2 : 4);
  auto tail = [&](size_t o){
    o = align(o); o += (size_t)M*4;          // BH
    o = align(o); o += (size_t)(M+1)*4;      // SO
    o = align(o); o += 256*4;                // part
    o = align(o); o += (size_t)(N+1)*4;      // offC
    o = align(o); o += list2B;               // list2
    return o;
  };
  size_t total2 = tail(align(align(hbB) + uhB) + (size_t)N*64*4);
  int VPREC = (ws_size >= total2) ? 1 : 0;

  char* ws = (char*)d_ws;
  size_t o = 0;
  unsigned short* hb = (unsigned short*)(ws + o); o = align(o + hbB);
  unsigned short* uh = (unsigned short*)(ws + o); o = align(o + uhB);
  float* vf = nullptr; unsigned short* vh = nullptr;
  if (VPREC){ vf = (float*)(ws + o);          o = align(o + (size_t)N*64*4); }
  else      { vh = (unsigned short*)(ws + o); o = align(o + (size_t)N*64*2); }
  int* BH   = (int*)(ws + o); o = align(o + (size_t)M*4);
  int* SO   = (int*)(ws + o); o = align(o + (size_t)(M+1)*4);
  int* part = (int*)(ws + o); o = align(o + 256*4);
  int* offC = (int*)(ws + o); o = align(o + (size_t)(N+1)*4);
  void* list2P = (void*)(ws + o); o = align(o + list2B);
  unsigned* packed = (unsigned*)out;   // d_out scratch; dead before k_updM

  dim3 blk(256);
  int nblkN  = (N + 255) / 256;        // 196
  int nblkU  = (N + 63) / 64;          // 782 (MFMA blocks)
  int nblkS1 = (M + 2047) / 2048;      // 98 (<=256 req by k_scan2)

  if (VPREC) k_encM<1><<<dim3(nblkU), blk, 0, stream>>>(x, encW1, encb1, encW2, encb2, msgW1,
                                                        hb, uh, vf, vh, N);
  else       k_encM<0><<<dim3(nblkU), blk, 0, stream>>>(x, encW1, encb1, encW2, encb2, msgW1,
                                                        hb, uh, vf, vh, N);
  k_hist<<<dim3(G1), blk, 0, stream>>>(ei, BH, E, N, nb1, nwords);
  k_scan1<<<dim3(nblkS1), blk, 0, stream>>>(BH, SO, part, M);
  k_scan2<<<dim3(1),      blk, 0, stream>>>(part, nblkS1, SO, M, E);
  k_pass2<<<dim3(G1),     blk, 0, stream>>>(ei, SO, part, packed, E, N, nb1, nwords);
  if (idx16){
    k_pass3<unsigned short><<<dim3(nb1), blk, 0, stream>>>(packed, SO, part, offC, (unsigned short*)list2P, N, nb1, M, E);
    if (VPREC) k_aggV<1,unsigned short><<<dim3(4096), blk, 0, stream>>>(uh, vf, vh, vf, vh, msgb1, msgW2, msgb2, offC, (unsigned short*)list2P, N);
    else       k_aggV<0,unsigned short><<<dim3(4096), blk, 0, stream>>>(uh, vf, vh, vf, vh, msgb1, msgW2, msgb2, offC, (unsigned short*)list2P, N);
  } else {
    k_pass3<int><<<dim3(nb1), blk, 0, stream>>>(packed, SO, part, offC, (int*)list2P, N, nb1, M, E);
    if (VPREC) k_aggV<1,int><<<dim3(4096), blk, 0, stream>>>(uh, vf, vh, vf, vh, msgb1, msgW2, msgb2, offC, (int*)list2P, N);
    else       k_aggV<0,int><<<dim3(4096), blk, 0, stream>>>(uh, vf, vh, vf, vh, msgb1, msgW2, msgb2, offC, (int*)list2P, N);
  }
  if (VPREC) k_updM<1><<<dim3(nblkU), blk, 0, stream>>>(hb, vf, vh, updW1, updb1, updW2, updb2, out, N);
  else       k_updM<0><<<dim3(nblkU), blk, 0, stream>>>(hb, vf, vh, updW1, updb1, updW2, updb2, out, N);
  k_tac<<<dim3(nblkN), blk, 0, stream>>>(tacW1, tacb1, tacW2, tacb2, tacW3, tacb3, out, N);
}

// Round 24
// 174.631 us; speedup vs baseline: 1.1700x; 1.0855x over previous
//
#include <hip/hip_runtime.h>
#include <hip/hip_bf16.h>

// BasketballGNN R24: aggV grid back to 2048 (R21 best: 59us; 4096 was 62) and
// tactical head fused into k_updM as 3 extra MFMA stages (t1/t2/out4), with tac
// weights staged into the dead uW1T LDS region after layer 1. Kills k_tac
// (~15us thread-per-node grid-starved kernel + gap + 12.8MB h2 round-trip).

__device__ inline float bflo(unsigned u){ return __uint_as_float(u << 16); }
__device__ inline float bfhi(unsigned u){ return __uint_as_float(u & 0xffff0000u); }
__device__ inline float gbf(const unsigned short* p){ return __uint_as_float(((unsigned)(*p)) << 16); }
__device__ inline unsigned short f2bu(float f){
  unsigned x = __float_as_uint(f);
  unsigned r = (x + 0x7fffu + ((x >> 16) & 1u)) >> 16;  // RNE
  return (unsigned short)r;
}

typedef __attribute__((ext_vector_type(8))) short short8v;
typedef __attribute__((ext_vector_type(4))) float float4v;

// detect edge-index width (int64 -> odd 32b words all zero). 1 = int32, 0 = int64.
__device__ inline int detect_i32(const int* ei, int nwords, int tid, int* sflag){
  if (tid == 0) *sflag = 0;
  __syncthreads();
  int acc = 0;
  for (int i = tid; i < nwords; i += 256)
    if (i & 1) acc |= ei[i];
  if (acc) atomicOr(sflag, 1);
  __syncthreads();
  return *sflag;
}

__device__ inline void load_rc32(const int* ei, int is32, int e, int E, int N, int& r, int& c){
  if (is32){ r = ei[e]; c = ei[(size_t)E + e]; }
  else     { r = ei[2*(size_t)e]; c = ei[2*((size_t)E + (size_t)e)]; }
  r = min(max(r, 0), N-1); c = min(max(c, 0), N-1);
}

// ------- k_encM: MFMA encoder + u,v (R21, unchanged) -------
template<int VPREC>
__global__ __launch_bounds__(256) void k_encM(
    const float* __restrict__ x,    // [N,6]
    const float* __restrict__ eW1, const float* __restrict__ eb1,
    const float* __restrict__ eW2, const float* __restrict__ eb2,
    const float* __restrict__ mW1,  // [128,64]
    unsigned short* __restrict__ hb,
    unsigned short* __restrict__ uh,
    float* __restrict__ vf, unsigned short* __restrict__ vh,
    int N)
{
  __shared__ unsigned short F_lds[64*40];
  __shared__ unsigned short W1T[64*40];
  __shared__ unsigned short W2T[64*72];
  __shared__ unsigned short loT[64*72];
  __shared__ unsigned short hiT[64*72];
  __shared__ unsigned short S_lds[4][16*72];
  __shared__ float b1s[64], b2s[64];

  int tid = threadIdx.x, lane = tid & 63, w = tid >> 6;
  int gbase = blockIdx.x * 64;

  for (int i = tid; i < 64*40; i += 256){
    int nl = i / 40, k = i % 40;
    int ng = gbase + nl;
    unsigned short val = 0;
    if (ng < N && k < 6) val = f2bu(x[(size_t)ng*6 + k]);
    F_lds[i] = val;
  }
  for (int i = tid; i < 64*40; i += 256){
    int j = i / 40, k = i % 40;
    W1T[i] = (k < 6) ? f2bu(eW1[k*64 + j]) : (unsigned short)0;
  }
  for (int i = tid; i < 64*64; i += 256){
    int k = i >> 6, c = i & 63;
    W2T[c*72 + k] = f2bu(eW2[i]);
    loT[c*72 + k] = f2bu(mW1[i]);
    hiT[c*72 + k] = f2bu(mW1[64*64 + i]);
  }
  if (tid < 64){ b1s[tid] = eb1[tid]; b2s[tid] = eb2[tid]; }
  __syncthreads();

  int r  = lane & 15;
  int kg = lane >> 4;
  int wb = w * 16;

  {
    short8v a = *reinterpret_cast<const short8v*>(&F_lds[(wb + r)*40 + kg*8]);
    float4v c0 = {0.f,0.f,0.f,0.f}, c1 = c0, c2 = c0, c3 = c0;
    short8v b0 = *reinterpret_cast<const short8v*>(&W1T[( 0 + r)*40 + kg*8]);
    short8v b1v= *reinterpret_cast<const short8v*>(&W1T[(16 + r)*40 + kg*8]);
    short8v b2v= *reinterpret_cast<const short8v*>(&W1T[(32 + r)*40 + kg*8]);
    short8v b3v= *reinterpret_cast<const short8v*>(&W1T[(48 + r)*40 + kg*8]);
    c0 = __builtin_amdgcn_mfma_f32_16x16x32_bf16(a, b0, c0, 0, 0, 0);
    c1 = __builtin_amdgcn_mfma_f32_16x16x32_bf16(a, b1v, c1, 0, 0, 0);
    c2 = __builtin_amdgcn_mfma_f32_16x16x32_bf16(a, b2v, c2, 0, 0, 0);
    c3 = __builtin_amdgcn_mfma_f32_16x16x32_bf16(a, b3v, c3, 0, 0, 0);
    float bb0 = b1s[ 0 + r], bb1 = b1s[16 + r], bb2 = b1s[32 + r], bb3 = b1s[48 + r];
    #pragma unroll
    for (int i = 0; i < 4; i++){
      int row = kg*4 + i;
      S_lds[w][row*72 +  0 + r] = f2bu(fmaxf(c0[i] + bb0, 0.f));
      S_lds[w][row*72 + 16 + r] = f2bu(fmaxf(c1[i] + bb1, 0.f));
      S_lds[w][row*72 + 32 + r] = f2bu(fmaxf(c2[i] + bb2, 0.f));
      S_lds[w][row*72 + 48 + r] = f2bu(fmaxf(c3[i] + bb3, 0.f));
    }
  }

  float hv[4][4];
  {
    float4v c0 = {0.f,0.f,0.f,0.f}, c1 = c0, c2 = c0, c3 = c0;
    #pragma unroll
    for (int kt = 0; kt < 2; kt++){
      short8v a2 = *reinterpret_cast<const short8v*>(&S_lds[w][r*72 + kt*32 + kg*8]);
      short8v d0 = *reinterpret_cast<const short8v*>(&W2T[( 0 + r)*72 + kt*32 + kg*8]);
      short8v d1 = *reinterpret_cast<const short8v*>(&W2T[(16 + r)*72 + kt*32 + kg*8]);
      short8v d2 = *reinterpret_cast<const short8v*>(&W2T[(32 + r)*72 + kt*32 + kg*8]);
      short8v d3 = *reinterpret_cast<const short8v*>(&W2T[(48 + r)*72 + kt*32 + kg*8]);
      c0 = __builtin_amdgcn_mfma_f32_16x16x32_bf16(a2, d0, c0, 0, 0, 0);
      c1 = __builtin_amdgcn_mfma_f32_16x16x32_bf16(a2, d1, c1, 0, 0, 0);
      c2 = __builtin_amdgcn_mfma_f32_16x16x32_bf16(a2, d2, c2, 0, 0, 0);
      c3 = __builtin_amdgcn_mfma_f32_16x16x32_bf16(a2, d3, c3, 0, 0, 0);
    }
    float bb0 = b2s[ 0 + r], bb1 = b2s[16 + r], bb2 = b2s[32 + r], bb3 = b2s[48 + r];
    #pragma unroll
    for (int i = 0; i < 4; i++){
      hv[0][i] = c0[i] + bb0; hv[1][i] = c1[i] + bb1;
      hv[2][i] = c2[i] + bb2; hv[3][i] = c3[i] + bb3;
    }
  }
  #pragma unroll
  for (int i = 0; i < 4; i++){
    int row = kg*4 + i;
    int ng = gbase + wb + row;
    unsigned short h0 = f2bu(hv[0][i]), h1 = f2bu(hv[1][i]);
    unsigned short h2 = f2bu(hv[2][i]), h3 = f2bu(hv[3][i]);
    if (ng < N){
      hb[(size_t)ng*64 +  0 + r] = h0;
      hb[(size_t)ng*64 + 16 + r] = h1;
      hb[(size_t)ng*64 + 32 + r] = h2;
      hb[(size_t)ng*64 + 48 + r] = h3;
    }
    S_lds[w][row*72 +  0 + r] = h0;
    S_lds[w][row*72 + 16 + r] = h1;
    S_lds[w][row*72 + 32 + r] = h2;
    S_lds[w][row*72 + 48 + r] = h3;
  }

  float4v u0 = {0.f,0.f,0.f,0.f}, u1 = u0, u2 = u0, u3 = u0;
  float4v v0 = u0, v1 = u0, v2 = u0, v3 = u0;
  #pragma unroll
  for (int kt = 0; kt < 2; kt++){
    short8v a3 = *reinterpret_cast<const short8v*>(&S_lds[w][r*72 + kt*32 + kg*8]);
    short8v l0 = *reinterpret_cast<const short8v*>(&loT[( 0 + r)*72 + kt*32 + kg*8]);
    short8v l1 = *reinterpret_cast<const short8v*>(&loT[(16 + r)*72 + kt*32 + kg*8]);
    short8v l2 = *reinterpret_cast<const short8v*>(&loT[(32 + r)*72 + kt*32 + kg*8]);
    short8v l3 = *reinterpret_cast<const short8v*>(&loT[(48 + r)*72 + kt*32 + kg*8]);
    short8v g0 = *reinterpret_cast<const short8v*>(&hiT[( 0 + r)*72 + kt*32 + kg*8]);
    short8v g1 = *reinterpret_cast<const short8v*>(&hiT[(16 + r)*72 + kt*32 + kg*8]);
    short8v g2 = *reinterpret_cast<const short8v*>(&hiT[(32 + r)*72 + kt*32 + kg*8]);
    short8v g3 = *reinterpret_cast<const short8v*>(&hiT[(48 + r)*72 + kt*32 + kg*8]);
    u0 = __builtin_amdgcn_mfma_f32_16x16x32_bf16(a3, l0, u0, 0, 0, 0);
    u1 = __builtin_amdgcn_mfma_f32_16x16x32_bf16(a3, l1, u1, 0, 0, 0);
    u2 = __builtin_amdgcn_mfma_f32_16x16x32_bf16(a3, l2, u2, 0, 0, 0);
    u3 = __builtin_amdgcn_mfma_f32_16x16x32_bf16(a3, l3, u3, 0, 0, 0);
    v0 = __builtin_amdgcn_mfma_f32_16x16x32_bf16(a3, g0, v0, 0, 0, 0);
    v1 = __builtin_amdgcn_mfma_f32_16x16x32_bf16(a3, g1, v1, 0, 0, 0);
    v2 = __builtin_amdgcn_mfma_f32_16x16x32_bf16(a3, g2, v2, 0, 0, 0);
    v3 = __builtin_amdgcn_mfma_f32_16x16x32_bf16(a3, g3, v3, 0, 0, 0);
  }
  #pragma unroll
  for (int i = 0; i < 4; i++){
    int ng = gbase + wb + kg*4 + i;
    if (ng < N){
      uh[(size_t)ng*64 +  0 + r] = f2bu(u0[i]);
      uh[(size_t)ng*64 + 16 + r] = f2bu(u1[i]);
      uh[(size_t)ng*64 + 32 + r] = f2bu(u2[i]);
      uh[(size_t)ng*64 + 48 + r] = f2bu(u3[i]);
      if (VPREC){
        vf[(size_t)ng*64 +  0 + r] = v0[i];
        vf[(size_t)ng*64 + 16 + r] = v1[i];
        vf[(size_t)ng*64 + 32 + r] = v2[i];
        vf[(size_t)ng*64 + 48 + r] = v3[i];
      } else {
        vh[(size_t)ng*64 +  0 + r] = f2bu(v0[i]);
        vh[(size_t)ng*64 + 16 + r] = f2bu(v1[i]);
        vh[(size_t)ng*64 + 32 + r] = f2bu(v2[i]);
        vh[(size_t)ng*64 + 48 + r] = f2bu(v3[i]);
      }
    }
  }
}

// ------- k_hist: coarse histogram (R14, unchanged) -------
__global__ __launch_bounds__(256) void k_hist(
    const int* __restrict__ ei,
    int* __restrict__ BH,
    int E, int N, int nb1, int nwords)
{
  __shared__ int hist[1024];
  __shared__ int sflag;
  int tid = threadIdx.x;
  for (int i = tid; i < nb1; i += 256) hist[i] = 0;
  int is32 = detect_i32(ei, nwords, tid, &sflag);
  int j = blockIdx.x;
  for (int e = j*256 + tid; e < E; e += 1024*256){
    int c = is32 ? ei[(size_t)E + e] : ei[2*((size_t)E + (size_t)e)];
    c = min(max(c, 0), N-1);
    atomicAdd(&hist[c >> 8], 1);
  }
  __syncthreads();
  int jm = ((j & 7) << 7) | (j >> 3);
  for (int i = tid; i < nb1; i += 256) BH[(size_t)i*1024 + jm] = hist[i];
}

// ---------------- scans ----------------
__global__ void k_scan1(const int* __restrict__ counts, int* __restrict__ offsets,
                        int* __restrict__ part, int M)
{
  __shared__ int tsum[256];
  int t = threadIdx.x;
  int base = blockIdx.x*2048 + t*8;
  int v[8]; int s = 0;
  #pragma unroll
  for (int i = 0; i < 8; i++){ int idx = base+i; v[i] = (idx < M) ? counts[idx] : 0; }
  #pragma unroll
  for (int i = 0; i < 8; i++){ int t0 = v[i]; v[i] = s; s += t0; }
  tsum[t] = s;
  __syncthreads();
  for (int d = 1; d < 256; d <<= 1){
    int y = (t >= d) ? tsum[t-d] : 0;
    __syncthreads();
    tsum[t] += y;
    __syncthreads();
  }
  int tpre = tsum[t] - s;
  #pragma unroll
  for (int i = 0; i < 8; i++){ int idx = base+i; if (idx < M) offsets[idx] = tpre + v[i]; }
  if (t == 255) part[blockIdx.x] = tsum[255];
}

__global__ void k_scan2(int* __restrict__ part, int nblk, int* __restrict__ offsets, int M, int E)
{
  __shared__ int tmp[256];
  int t = threadIdx.x;
  int v = (t < nblk) ? part[t] : 0;
  tmp[t] = v;
  __syncthreads();
  for (int d = 1; d < 256; d <<= 1){
    int y = (t >= d) ? tmp[t-d] : 0;
    __syncthreads();
    tmp[t] += y;
    __syncthreads();
  }
  if (t < nblk) part[t] = tmp[t] - v;   // exclusive
  if (t == 0) offsets[M] = E;
}

// ------- pass2: scatter to coarse buckets -------
__global__ __launch_bounds__(256) void k_pass2(
    const int* __restrict__ ei,
    const int* __restrict__ SO, const int* __restrict__ part,
    unsigned* __restrict__ packed,
    int E, int N, int nb1, int nwords)
{
  __shared__ int cur[1024];
  __shared__ int sflag;
  int tid = threadIdx.x;
  int j = blockIdx.x;
  int jm = ((j & 7) << 7) | (j >> 3);
  for (int i = tid; i < nb1; i += 256){
    int idx = i*1024 + jm;
    cur[i] = SO[idx] + part[idx >> 11];
  }
  int is32 = detect_i32(ei, nwords, tid, &sflag);
  for (int e = j*256 + tid; e < E; e += 1024*256){
    int r, c; load_rc32(ei, is32, e, E, N, r, c);
    int bin = c >> 8, low = c & 255;
    int pos = atomicAdd(&cur[bin], 1);
    packed[pos] = ((unsigned)low << 24) | (unsigned)r;
  }
}

// ------- pass3: bucket-local counting sort -> node-major CSR -------
template<typename IT>
__global__ __launch_bounds__(256) void k_pass3(
    const unsigned* __restrict__ packed,
    const int* __restrict__ SO, const int* __restrict__ part,
    int* __restrict__ offC,
    IT* __restrict__ list2,
    int N, int nb1, int M, int E)
{
  __shared__ int hist[256], scn[256], cur[256];
  int tid = threadIdx.x;
  int bin = blockIdx.x;
  int i0 = bin*1024;
  int i1 = (bin+1)*1024;
  int segStart = SO[i0] + part[i0 >> 11];
  int segEnd   = (i1 >= M) ? E : (SO[i1] + part[i1 >> 11]);

  hist[tid] = 0;
  __syncthreads();
  for (int p = segStart + tid; p < segEnd; p += 256)
    atomicAdd(&hist[packed[p] >> 24], 1);
  __syncthreads();
  int own = hist[tid];
  scn[tid] = own;
  __syncthreads();
  for (int d = 1; d < 256; d <<= 1){
    int y = (tid >= d) ? scn[tid-d] : 0;
    __syncthreads();
    scn[tid] += y;
    __syncthreads();
  }
  int excl = scn[tid] - own;
  cur[tid] = excl;
  int node = bin*256 + tid;
  if (node < N) offC[node] = segStart + excl;
  if (bin == nb1-1 && tid == 0) offC[N] = E;
  __syncthreads();
  for (int p = segStart + tid; p < segEnd; p += 256){
    unsigned u = packed[p];
    int pos = atomicAdd(&cur[u >> 24], 1);
    list2[segStart + pos] = (IT)(u & 0xFFFFFFu);
  }
}

// ------- k_aggV: vectorized aggregation (R21 body, grid 2048) -------
template<int VPREC, typename IT>
__global__ __launch_bounds__(256) void k_aggV(
    const unsigned short* __restrict__ uh,  // [N,64] bf16
    const float* vfin, const unsigned short* vhin,
    float* aggf, unsigned short* aggh,
    const float* __restrict__ b1,
    const float* __restrict__ W2,   // [64,64]
    const float* __restrict__ b2,
    const int* __restrict__ offC, const IT* __restrict__ list2, int N)
{
  __shared__ float sS[4][64];
  int tid = threadIdx.x, lane = tid & 63, w = tid >> 6;
  int rsub = lane >> 3, fo = lane & 7;
  float w2c[64];
  #pragma unroll
  for (int j = 0; j < 64; j++) w2c[j] = W2[j*64 + lane];
  float b2l = b2[lane];
  float b1o[8];
  #pragma unroll
  for (int k = 0; k < 8; k++) b1o[k] = b1[fo*8 + k];

  for (int node = blockIdx.x*4 + w; node < N; node += gridDim.x*4){
    int base = offC[node];
    int deg  = offC[node+1] - base;

    float vc8[8];
    #pragma unroll
    for (int k = 0; k < 8; k++)
      vc8[k] = (VPREC ? vfin[(size_t)node*64 + fo*8 + k]
                      : gbf(vhin + (size_t)node*64 + fo*8 + k)) + b1o[k];

    float acc8[8];
    #pragma unroll
    for (int k = 0; k < 8; k++) acc8[k] = 0.f;

    #pragma unroll 1
    for (int cs = 0; cs < deg; cs += 64){
      int clen = min(deg - cs, 64);
      int myidx = (lane < clen) ? (int)list2[base + cs + lane] : 0;
      #pragma unroll 1
      for (int s = 0; s < clen; s += 8){
        int ss = min(s + rsub, clen - 1);
        int r  = __shfl(myidx, ss);
        bool valid = (s + rsub) < clen;
        const uint4* up = reinterpret_cast<const uint4*>(uh + (size_t)r*64 + fo*8);
        uint4 d = *up;
        float f0 = bflo(d.x), f1 = bfhi(d.x), f2 = bflo(d.y), f3 = bfhi(d.y);
        float f4 = bflo(d.z), f5 = bfhi(d.z), f6 = bflo(d.w), f7 = bfhi(d.w);
        float r0 = fmaxf(f0 + vc8[0], 0.f), r1 = fmaxf(f1 + vc8[1], 0.f);
        float r2 = fmaxf(f2 + vc8[2], 0.f), r3 = fmaxf(f3 + vc8[3], 0.f);
        float r4 = fmaxf(f4 + vc8[4], 0.f), r5 = fmaxf(f5 + vc8[5], 0.f);
        float r6 = fmaxf(f6 + vc8[6], 0.f), r7 = fmaxf(f7 + vc8[7], 0.f);
        if (valid){
          acc8[0] += r0; acc8[1] += r1; acc8[2] += r2; acc8[3] += r3;
          acc8[4] += r4; acc8[5] += r5; acc8[6] += r6; acc8[7] += r7;
        }
      }
    }

    #pragma unroll
    for (int m = 8; m < 64; m <<= 1){
      #pragma unroll
      for (int k = 0; k < 8; k++) acc8[k] += __shfl_xor(acc8[k], m);
    }
    float inv = (deg > 0) ? 1.0f/(float)deg : 0.f;
    if (rsub == 0){
      float4 a, b;
      a.x = acc8[0]*inv; a.y = acc8[1]*inv; a.z = acc8[2]*inv; a.w = acc8[3]*inv;
      b.x = acc8[4]*inv; b.y = acc8[5]*inv; b.z = acc8[6]*inv; b.w = acc8[7]*inv;
      float4* sp = reinterpret_cast<float4*>(&sS[w][fo*8]);
      sp[0] = a; sp[1] = b;
    }
    const float4* s4 = reinterpret_cast<const float4*>(&sS[w][0]);
    float m0 = b2l, m1 = 0.f, m2 = 0.f, m3 = 0.f;
    #pragma unroll
    for (int q = 0; q < 16; q += 4){
      float4 v0 = s4[q], v1 = s4[q+1], v2 = s4[q+2], v3 = s4[q+3];
      m0 += v0.x*w2c[4*q+0]  + v0.y*w2c[4*q+1]  + v0.z*w2c[4*q+2]  + v0.w*w2c[4*q+3];
      m1 += v1.x*w2c[4*q+4]  + v1.y*w2c[4*q+5]  + v1.z*w2c[4*q+6]  + v1.w*w2c[4*q+7];
      m2 += v2.x*w2c[4*q+8]  + v2.y*w2c[4*q+9]  + v2.z*w2c[4*q+10] + v2.w*w2c[4*q+11];
      m3 += v3.x*w2c[4*q+12] + v3.y*w2c[4*q+13] + v3.z*w2c[4*q+14] + v3.w*w2c[4*q+15];
    }
    float m = (m0 + m1) + (m2 + m3);
    if (deg == 0) m = 0.f;
    if (VPREC) aggf[(size_t)node*64 + lane] = m;
    else       aggh[(size_t)node*64 + lane] = f2bu(m);
  }
}

// ------- k_updM: MFMA update MLP + fused tactical head -------
// After layer 1, uW1T's LDS region is dead; tac weights are staged there
// (T1T @0: 64x40, T2T @2560: 16x72, T3T @3712: 16x40 u16). h2/t1/t2 cycle through
// the per-wave S_lds slice with in-wave DS ordering (no barriers needed there).
template<int VPREC>
__global__ __launch_bounds__(256) void k_updM(
    const unsigned short* __restrict__ hb,
    const float* __restrict__ aggf, const unsigned short* __restrict__ aggh,
    const float* __restrict__ uW1, const float* __restrict__ ub1,
    const float* __restrict__ uW2, const float* __restrict__ ub2,
    const float* __restrict__ tW1, const float* __restrict__ tb1,
    const float* __restrict__ tW2, const float* __restrict__ tb2,
    const float* __restrict__ tW3, const float* __restrict__ tb3,
    float* __restrict__ out, int N)
{
  __shared__ unsigned short F_lds[64*136];
  __shared__ unsigned short W1T[64*136];   // uW1T; reused for tac weights after layer 1
  __shared__ unsigned short W2T[32*72];
  __shared__ unsigned short S_lds[4][16*72];
  __shared__ float b1s[64], b2s[32];
  __shared__ float tb1s[64], tb2s[16], tb3s[4];

  int tid = threadIdx.x, lane = tid & 63, w = tid >> 6;
  int gbase = blockIdx.x * 64;

  for (int i = tid; i < 64*128; i += 256){
    int nl = i >> 7, f = i & 127;
    int ng = gbase + nl;
    unsigned short val = 0;
    if (ng < N){
      if (f < 64) val = hb[(size_t)ng*64 + f];
      else        val = VPREC ? f2bu(aggf[(size_t)ng*64 + (f-64)]) : aggh[(size_t)ng*64 + (f-64)];
    }
    F_lds[nl*136 + f] = val;
  }
  for (int i = tid; i < 128*64; i += 256){
    int k = i >> 6, j = i & 63;
    W1T[j*136 + k] = f2bu(uW1[i]);
  }
  for (int i = tid; i < 64*32; i += 256){
    int k = i >> 5, c = i & 31;
    W2T[c*72 + k] = f2bu(uW2[i]);
  }
  if (tid < 64) b1s[tid] = ub1[tid];
  if (tid < 32) b2s[tid] = ub2[tid];
  __syncthreads();

  int r  = lane & 15;
  int kg = lane >> 4;
  int wb = w * 16;

  // ---- layer 1: S1 = relu(F@uW1 + b1) ----
  float4v acc0 = {0.f,0.f,0.f,0.f}, acc1 = acc0, acc2 = acc0, acc3 = acc0;
  #pragma unroll
  for (int kt = 0; kt < 4; kt++){
    short8v a = *reinterpret_cast<const short8v*>(&F_lds[(wb + r)*136 + kt*32 + kg*8]);
    short8v b0 = *reinterpret_cast<const short8v*>(&W1T[( 0 + r)*136 + kt*32 + kg*8]);
    short8v b1v= *reinterpret_cast<const short8v*>(&W1T[(16 + r)*136 + kt*32 + kg*8]);
    short8v b2v= *reinterpret_cast<const short8v*>(&W1T[(32 + r)*136 + kt*32 + kg*8]);
    short8v b3v= *reinterpret_cast<const short8v*>(&W1T[(48 + r)*136 + kt*32 + kg*8]);
    acc0 = __builtin_amdgcn_mfma_f32_16x16x32_bf16(a, b0, acc0, 0, 0, 0);
    acc1 = __builtin_amdgcn_mfma_f32_16x16x32_bf16(a, b1v, acc1, 0, 0, 0);
    acc2 = __builtin_amdgcn_mfma_f32_16x16x32_bf16(a, b2v, acc2, 0, 0, 0);
    acc3 = __builtin_amdgcn_mfma_f32_16x16x32_bf16(a, b3v, acc3, 0, 0, 0);
  }
  {
    float bb0 = b1s[ 0 + r], bb1 = b1s[16 + r], bb2 = b1s[32 + r], bb3 = b1s[48 + r];
    #pragma unroll
    for (int i = 0; i < 4; i++){
      int row = kg*4 + i;
      S_lds[w][row*72 +  0 + r] = f2bu(fmaxf(acc0[i] + bb0, 0.f));
      S_lds[w][row*72 + 16 + r] = f2bu(fmaxf(acc1[i] + bb1, 0.f));
      S_lds[w][row*72 + 32 + r] = f2bu(fmaxf(acc2[i] + bb2, 0.f));
      S_lds[w][row*72 + 48 + r] = f2bu(fmaxf(acc3[i] + bb3, 0.f));
    }
  }
  __syncthreads();   // all waves done reading F_lds / W1T

  // ---- stage tac weights into dead W1T region ----
  for (int i = tid; i < 64*40; i += 256){
    int j = i / 40, k = i % 40;
    W1T[i] = (k < 32) ? f2bu(tW1[k*64 + j]) : (unsigned short)0;
  }
  for (int i = tid; i < 16*72; i += 256){
    int c = i / 72, k = i % 72;
    W1T[2560 + i] = (k < 64) ? f2bu(tW2[k*16 + c]) : (unsigned short)0;
  }
  for (int i = tid; i < 16*40; i += 256){
    int c = i / 40, k = i % 40;
    W1T[3712 + i] = (c < 4 && k < 16) ? f2bu(tW3[k*4 + c]) : (unsigned short)0;
  }
  if (tid < 64) tb1s[tid] = tb1[tid];
  if (tid < 16) tb2s[tid] = tb2[tid];
  if (tid < 4)  tb3s[tid] = tb3[tid];
  __syncthreads();

  // ---- layer 2: h2 = S1@uW2 + b2; write to out, stage bf16 into S_lds ----
  float4v d0 = {0.f,0.f,0.f,0.f}, d1 = d0;
  #pragma unroll
  for (int kt = 0; kt < 2; kt++){
    short8v a2 = *reinterpret_cast<const short8v*>(&S_lds[w][r*72 + kt*32 + kg*8]);
    short8v c0 = *reinterpret_cast<const short8v*>(&W2T[( 0 + r)*72 + kt*32 + kg*8]);
    short8v c1 = *reinterpret_cast<const short8v*>(&W2T[(16 + r)*72 + kt*32 + kg*8]);
    d0 = __builtin_amdgcn_mfma_f32_16x16x32_bf16(a2, c0, d0, 0, 0, 0);
    d1 = __builtin_amdgcn_mfma_f32_16x16x32_bf16(a2, c1, d1, 0, 0, 0);
  }
  {
    float bb0 = b2s[ 0 + r], bb1 = b2s[16 + r];
    #pragma unroll
    for (int i = 0; i < 4; i++){
      int row = kg*4 + i;
      int ng = gbase + wb + row;
      float h20 = d0[i] + bb0, h21 = d1[i] + bb1;
      if (ng < N){
        out[(size_t)ng*32 +  0 + r] = h20;
        out[(size_t)ng*32 + 16 + r] = h21;
      }
      S_lds[w][row*72 +  0 + r] = f2bu(h20);   // h2 staged (cols 0..31)
      S_lds[w][row*72 + 16 + r] = f2bu(h21);
    }
  }

  // ---- tac layer 1: t1 = relu(h2@tW1 + tb1), K=32, 4 n-tiles ----
  {
    short8v ah = *reinterpret_cast<const short8v*>(&S_lds[w][r*72 + kg*8]);  // K=32
    float4v t0 = {0.f,0.f,0.f,0.f}, t1v = t0, t2v = t0, t3v = t0;
    short8v e0 = *reinterpret_cast<const short8v*>(&W1T[( 0 + r)*40 + kg*8]);
    short8v e1 = *reinterpret_cast<const short8v*>(&W1T[(16 + r)*40 + kg*8]);
    short8v e2 = *reinterpret_cast<const short8v*>(&W1T[(32 + r)*40 + kg*8]);
    short8v e3 = *reinterpret_cast<const short8v*>(&W1T[(48 + r)*40 + kg*8]);
    t0  = __builtin_amdgcn_mfma_f32_16x16x32_bf16(ah, e0, t0, 0, 0, 0);
    t1v = __builtin_amdgcn_mfma_f32_16x16x32_bf16(ah, e1, t1v, 0, 0, 0);
    t2v = __builtin_amdgcn_mfma_f32_16x16x32_bf16(ah, e2, t2v, 0, 0, 0);
    t3v = __builtin_amdgcn_mfma_f32_16x16x32_bf16(ah, e3, t3v, 0, 0, 0);
    float bb0 = tb1s[ 0 + r], bb1 = tb1s[16 + r], bb2 = tb1s[32 + r], bb3 = tb1s[48 + r];
    #pragma unroll
    for (int i = 0; i < 4; i++){
      int row = kg*4 + i;
      S_lds[w][row*72 +  0 + r] = f2bu(fmaxf(t0[i]  + bb0, 0.f));
      S_lds[w][row*72 + 16 + r] = f2bu(fmaxf(t1v[i] + bb1, 0.f));
      S_lds[w][row*72 + 32 + r] = f2bu(fmaxf(t2v[i] + bb2, 0.f));
      S_lds[w][row*72 + 48 + r] = f2bu(fmaxf(t3v[i] + bb3, 0.f));
    }
  }

  // ---- tac layer 2: t2 = relu(t1@tW2 + tb2), K=64 (2 steps), 1 n-tile ----
  {
    float4v e = {0.f,0.f,0.f,0.f};
    #pragma unroll
    for (int kt = 0; kt < 2; kt++){
      short8v a4 = *reinterpret_cast<const short8v*>(&S_lds[w][r*72 + kt*32 + kg*8]);
      short8v c4 = *reinterpret_cast<const short8v*>(&W1T[2560 + r*72 + kt*32 + kg*8]);
      e = __builtin_amdgcn_mfma_f32_16x16x32_bf16(a4, c4, e, 0, 0, 0);
    }
    float bb = tb2s[r];
    #pragma unroll
    for (int i = 0; i < 4; i++){
      int row = kg*4 + i;
      S_lds[w][row*72 + r]      = f2bu(fmaxf(e[i] + bb, 0.f));  // t2 cols 0..15
      S_lds[w][row*72 + 16 + r] = 0;                            // zero-pad K 16..31
    }
  }

  // ---- tac layer 3: out4 = t2@tW3 + tb3, K=32 (1 step), cols 0..3 valid ----
  {
    short8v a5 = *reinterpret_cast<const short8v*>(&S_lds[w][r*72 + kg*8]);
    short8v c5 = *reinterpret_cast<const short8v*>(&W1T[3712 + r*40 + kg*8]);
    float4v f = {0.f,0.f,0.f,0.f};
    f = __builtin_amdgcn_mfma_f32_16x16x32_bf16(a5, c5, f, 0, 0, 0);
    if (r < 4){
      float bb = tb3s[r];
      #pragma unroll
      for (int i = 0; i < 4; i++){
        int ng = gbase + wb + kg*4 + i;
        if (ng < N) out[(size_t)N*32 + (size_t)ng*4 + r] = f[i] + bb;
      }
    }
  }
}

extern "C" void kernel_launch(void* const* d_in, const int* in_sizes, int n_in,
                              void* d_out, int out_size, void* d_ws, size_t ws_size,
                              hipStream_t stream)
{
  const float* x     = (const float*)d_in[0];
  const int*   ei    = (const int*)d_in[1];
  const float* encW1 = (const float*)d_in[2];
  const float* encb1 = (const float*)d_in[3];
  const float* encW2 = (const float*)d_in[4];
  const float* encb2 = (const float*)d_in[5];
  const float* msgW1 = (const float*)d_in[6];
  const float* msgb1 = (const float*)d_in[7];
  const float* msgW2 = (const float*)d_in[8];
  const float* msgb2 = (const float*)d_in[9];
  const float* updW1 = (const float*)d_in[10];
  const float* updb1 = (const float*)d_in[11];
  const float* updW2 = (const float*)d_in[12];
  const float* updb2 = (const float*)d_in[13];
  const float* tacW1 = (const float*)d_in[14];
  const float* tacb1 = (const float*)d_in[15];
  const float* tacW2 = (const float*)d_in[16];
  const float* tacb2 = (const float*)d_in[17];
  const float* tacW3 = (const float*)d_in[18];
  const float* tacb3 = (const float*)d_in[19];

  int N = in_sizes[0] / 6;
  int E = in_sizes[1] / 2;
  float* out = (float*)d_out;
  int idx16 = (N <= 65535) ? 1 : 0;
  int nwords = (2*E < 8192) ? 2*E : 8192;

  int nb1 = (N + 255) >> 8;            // 196 for N=50k
  const int G1 = 1024;                 // jm hardcodes 1024
  int M   = nb1 * G1;

  auto align = [](size_t v){ return (v + 255) & ~(size_t)255; };
  size_t hbB = (size_t)N*64*2, uhB = (size_t)N*64*2;
  size_t list2B = (size_t)E * (idx16 ? 2 : 4);
  auto tail = [&](size_t o){
    o = align(o); o += (size_t)M*4;          // BH
    o = align(o); o += (size_t)(M+1)*4;      // SO
    o = align(o); o += 256*4;                // part
    o = align(o); o += (size_t)(N+1)*4;      // offC
    o = align(o); o += list2B;               // list2
    return o;
  };
  size_t total2 = tail(align(align(hbB) + uhB) + (size_t)N*64*4);
  int VPREC = (ws_size >= total2) ? 1 : 0;

  char* ws = (char*)d_ws;
  size_t o = 0;
  unsigned short* hb = (unsigned short*)(ws + o); o = align(o + hbB);
  unsigned short* uh = (unsigned short*)(ws + o); o = align(o + uhB);
  float* vf = nullptr; unsigned short* vh = nullptr;
  if (VPREC){ vf = (float*)(ws + o);          o = align(o + (size_t)N*64*4); }
  else      { vh = (unsigned short*)(ws + o); o = align(o + (size_t)N*64*2); }
  int* BH   = (int*)(ws + o); o = align(o + (size_t)M*4);
  int* SO   = (int*)(ws + o); o = align(o + (size_t)(M+1)*4);
  int* part = (int*)(ws + o); o = align(o + 256*4);
  int* offC = (int*)(ws + o); o = align(o + (size_t)(N+1)*4);
  void* list2P = (void*)(ws + o); o = align(o + list2B);
  unsigned* packed = (unsigned*)out;   // d_out scratch; dead before k_updM

  dim3 blk(256);
  int nblkU  = (N + 63) / 64;          // 782 (MFMA blocks)
  int nblkS1 = (M + 2047) / 2048;      // 98 (<=256 req by k_scan2)

  if (VPREC) k_encM<1><<<dim3(nblkU), blk, 0, stream>>>(x, encW1, encb1, encW2, encb2, msgW1,
                                                        hb, uh, vf, vh, N);
  else       k_encM<0><<<dim3(nblkU), blk, 0, stream>>>(x, encW1, encb1, encW2, encb2, msgW1,
                                                        hb, uh, vf, vh, N);
  k_hist<<<dim3(G1), blk, 0, stream>>>(ei, BH, E, N, nb1, nwords);
  k_scan1<<<dim3(nblkS1), blk, 0, stream>>>(BH, SO, part, M);
  k_scan2<<<dim3(1),      blk, 0, stream>>>(part, nblkS1, SO, M, E);
  k_pass2<<<dim3(G1),     blk, 0, stream>>>(ei, SO, part, packed, E, N, nb1, nwords);
  if (idx16){
    k_pass3<unsigned short><<<dim3(nb1), blk, 0, stream>>>(packed, SO, part, offC, (unsigned short*)list2P, N, nb1, M, E);
    if (VPREC) k_aggV<1,unsigned short><<<dim3(2048), blk, 0, stream>>>(uh, vf, vh, vf, vh, msgb1, msgW2, msgb2, offC, (unsigned short*)list2P, N);
    else       k_aggV<0,unsigned short><<<dim3(2048), blk, 0, stream>>>(uh, vf, vh, vf, vh, msgb1, msgW2, msgb2, offC, (unsigned short*)list2P, N);
  } else {
    k_pass3<int><<<dim3(nb1), blk, 0, stream>>>(packed, SO, part, offC, (int*)list2P, N, nb1, M, E);
    if (VPREC) k_aggV<1,int><<<dim3(2048), blk, 0, stream>>>(uh, vf, vh, vf, vh, msgb1, msgW2, msgb2, offC, (int*)list2P, N);
    else       k_aggV<0,int><<<dim3(2048), blk, 0, stream>>>(uh, vf, vh, vf, vh, msgb1, msgW2, msgb2, offC, (int*)list2P, N);
  }
  if (VPREC) k_updM<1><<<dim3(nblkU), blk, 0, stream>>>(hb, vf, vh, updW1, updb1, updW2, updb2,
                                                        tacW1, tacb1, tacW2, tacb2, tacW3, tacb3,
                                                        out, N);
  else       k_updM<0><<<dim3(nblkU), blk, 0, stream>>>(hb, vf, vh, updW1, updb1, updW2, updb2,
                                                        tacW1, tacb1, tacW2, tacb2, tacW3, tacb3,
                                                        out, N);
}